// Round 17
// baseline (354.501 us; speedup 1.0000x reference)
//
#include <hip/hip_runtime.h>

typedef __bf16 bf16;
typedef __attribute__((ext_vector_type(8))) __bf16 bf16x8;
typedef __attribute__((ext_vector_type(2))) __bf16 bf16x2;
typedef __attribute__((ext_vector_type(4))) float f32x4;
typedef __attribute__((ext_vector_type(4))) int int4v;

typedef __attribute__((address_space(1))) const void gconst_t;
typedef __attribute__((address_space(3))) void lvoid_t;

#define SEQ 4096
#define D_IN 2048
#define NHEADS 16
// SCALE * log2(e): attention computed in exp2 domain
#define QSCALE (0.08838834764831843f * 1.4426950408889634f)
#define RMS_EPS 1e-6f
#define QKV_N 3136   // 2048 (q) + 1088 (kv_full)

__device__ inline unsigned pack2bf(float a, float b) {
    bf16x2 t; t[0] = (bf16)a; t[1] = (bf16)b;
    return __builtin_bit_cast(unsigned, t);
}

// ---------------------------------------------------------------- fused conversions
__device__ inline void conv_seg(const float* __restrict__ in, bf16* __restrict__ out,
                                int n, int i0, int stride) {
    for (int i = i0; i < n; i += stride) {
        float4 v = *reinterpret_cast<const float4*>(in + i);
        bf16 o[4];
        o[0] = (bf16)v.x; o[1] = (bf16)v.y; o[2] = (bf16)v.z; o[3] = (bf16)v.w;
        *reinterpret_cast<uint2*>(out + i) = *reinterpret_cast<uint2*>(o);
    }
}

__global__ __launch_bounds__(256) void convert_all_kernel(
    const float* __restrict__ xs,  const float* __restrict__ wqs,
    const float* __restrict__ was, const float* __restrict__ wbs,
    const float* __restrict__ wos,
    bf16* __restrict__ xd, bf16* __restrict__ wqd, bf16* __restrict__ wad,
    bf16* __restrict__ wbd, bf16* __restrict__ wod) {
    int i0 = (blockIdx.x * 256 + threadIdx.x) * 4;
    int stride = gridDim.x * 256 * 4;
    conv_seg(xs,  xd,  4096 * 2048, i0, stride);
    conv_seg(wqs, wqd, 2048 * 2048, i0, stride);
    conv_seg(was, wad, 1088 * 2048, i0, stride);
    conv_seg(wbs, wbd, 3072 * 1024, i0, stride);
    conv_seg(wos, wod, 2048 * 2048, i0, stride);
}

// ---------------------------------------------------------------- 256-wide GEMM, counted-vmcnt 2-barrier schedule
// (round-7/11/14 proven schedule: BK=64, double-buffered, vmcnt(8)/(6))
// + T1 XCD-chunked block swizzle (all grids are multiples of 8 -> bijective):
//   each XCD gets a contiguous chunk of linear ids so blocks sharing an
//   A-row-panel land on the same XCD's L2.
template<int BN, bool BF16_OUT>
__global__ __launch_bounds__(512, 2) void gemm256_kernel(
    const bf16* __restrict__ A, const bf16* __restrict__ B, void* __restrict__ Cout,
    int M, int N, int K) {
    constexpr int CB = BN / 64;      // B stage loads per thread (4 or 2)
    constexpr int NF = BN / 64;      // n-frags per wave (4 or 2)
    constexpr int WC = BN / 4;       // cols per wave
    __shared__ __align__(16) bf16 Al[2][256 * 64];
    __shared__ __align__(16) bf16 Bl[2][BN * 64];

    int t    = threadIdx.x;
    int lane = t & 63;
    int w    = t >> 6;        // 0..7
    int wr   = w >> 2;        // 0..1
    int wc   = w & 3;         // 0..3
    int l15  = lane & 15;
    int g    = lane >> 4;

    // XCD-chunked swizzle (bijective: nwg % 8 == 0 for all launches here)
    int nwg = gridDim.x * gridDim.y;
    int lid = (int)blockIdx.x + (int)gridDim.x * (int)blockIdx.y;
    int cpx = nwg >> 3;
    int nid = (lid & 7) * cpx + (lid >> 3);
    int bx  = nid % (int)gridDim.x;
    int by  = nid / (int)gridDim.x;
    int m0 = by * 256;
    int n0 = bx * BN;

    f32x4 acc[8][NF] = {};

    auto stage = [&](int kt, int buf) {
        int k0 = kt << 6;
        #pragma unroll
        for (int c = 0; c < 4; c++) {           // A: 256 rows x 64 cols
            int idx = c * 512 + t;
            int r = idx >> 3;
            int u = (idx & 7) ^ (r & 7);
            const bf16* ga = A + (size_t)(m0 + r) * K + k0 + u * 8;
            __builtin_amdgcn_global_load_lds((gconst_t*)ga,
                (lvoid_t*)&Al[buf][(c * 512 + w * 64) * 8], 16, 0, 0);
        }
        #pragma unroll
        for (int c = 0; c < CB; c++) {          // B: BN rows x 64 cols
            int idx = c * 512 + t;
            int r = idx >> 3;
            int u = (idx & 7) ^ (r & 7);
            int br = n0 + r; if (br >= N) br = N - 1;
            const bf16* gb = B + (size_t)br * K + k0 + u * 8;
            __builtin_amdgcn_global_load_lds((gconst_t*)gb,
                (lvoid_t*)&Bl[buf][(c * 512 + w * 64) * 8], 16, 0, 0);
        }
    };

    int nt = K >> 6;
    stage(0, 0);
    for (int kt = 0; kt < nt; ++kt) {
        int buf = kt & 1;
        if (kt + 1 < nt) {
            stage(kt + 1, buf ^ 1);
            __builtin_amdgcn_sched_barrier(0);
            if constexpr (BN == 256) asm volatile("s_waitcnt vmcnt(8)" ::: "memory");
            else                     asm volatile("s_waitcnt vmcnt(6)" ::: "memory");
            __builtin_amdgcn_sched_barrier(0);
        } else {
            __builtin_amdgcn_sched_barrier(0);
            asm volatile("s_waitcnt vmcnt(0)" ::: "memory");
            __builtin_amdgcn_sched_barrier(0);
        }
        __builtin_amdgcn_s_barrier();

        #pragma unroll
        for (int ks = 0; ks < 2; ++ks) {
            bf16x8 af[8], bfv[NF];
            #pragma unroll
            for (int mt = 0; mt < 8; mt++) {
                int ra = wr * 128 + mt * 16 + l15;
                int u = (ks * 4 + g) ^ (ra & 7);
                af[mt] = *reinterpret_cast<const bf16x8*>(&Al[buf][ra * 64 + u * 8]);
            }
            #pragma unroll
            for (int nf = 0; nf < NF; nf++) {
                int rb = wc * WC + nf * 16 + l15;
                int u = (ks * 4 + g) ^ (rb & 7);
                bfv[nf] = *reinterpret_cast<const bf16x8*>(&Bl[buf][rb * 64 + u * 8]);
            }
            __builtin_amdgcn_s_setprio(1);
            #pragma unroll
            for (int mt = 0; mt < 8; mt++)
                #pragma unroll
                for (int nf = 0; nf < NF; nf++)
                    acc[mt][nf] = __builtin_amdgcn_mfma_f32_16x16x32_bf16(af[mt], bfv[nf], acc[mt][nf], 0, 0, 0);
            __builtin_amdgcn_s_setprio(0);
        }
        __builtin_amdgcn_s_barrier();
    }

    #pragma unroll
    for (int mt = 0; mt < 8; mt++) {
        #pragma unroll
        for (int nf = 0; nf < NF; nf++) {
            int col = n0 + wc * WC + nf * 16 + l15;
            if (col < N) {
                #pragma unroll
                for (int r = 0; r < 4; r++) {
                    int row = m0 + wr * 128 + mt * 16 + g * 4 + r;
                    if (BF16_OUT)
                        ((bf16*)Cout)[(size_t)row * N + col] = (bf16)acc[mt][nf][r];
                    else
                        ((float*)Cout)[(size_t)row * N + col] = acc[mt][nf][r];
                }
            }
        }
    }
}

// ---------------------------------------------------------------- fused q+kv prep
__global__ __launch_bounds__(256) void prep_qkv_kernel(
    bf16* __restrict__ qkv, const float* __restrict__ w,
    const float* __restrict__ cosb, const float* __restrict__ sinb,
    bf16* __restrict__ kvnorm, bf16* __restrict__ kpe) {
    __shared__ float red[4];
    int s = blockIdx.x;
    int t = threadIdx.x;

    // ---- kv part
    const bf16* src = qkv + (size_t)s * QKV_N + 2048;
    float f[4];
    {
        uint2 raw = *reinterpret_cast<const uint2*>(src + t * 4);
        bf16* vb = reinterpret_cast<bf16*>(&raw);
        float ss = 0.f;
        #pragma unroll
        for (int j = 0; j < 4; j++) { f[j] = (float)vb[j]; ss += f[j] * f[j]; }
        #pragma unroll
        for (int m = 1; m < 64; m <<= 1) ss += __shfl_xor(ss, m);
        if ((t & 63) == 0) red[t >> 6] = ss;
    }
    __syncthreads();
    float tot = red[0] + red[1] + red[2] + red[3];
    float rms = rsqrtf(tot * (1.0f / 1024.0f) + RMS_EPS);
    bf16 o[4];
    #pragma unroll
    for (int j = 0; j < 4; j++) o[j] = (bf16)(f[j] * rms * w[t*4 + j]);
    *reinterpret_cast<uint2*>(kvnorm + (size_t)s * 1024 + t * 4) = *reinterpret_cast<uint2*>(o);
    if (t < 16) {
        float e[4];
        #pragma unroll
        for (int j = 0; j < 4; j++) e[j] = (float)src[1024 + t*4 + j];
        int ib = t * 2;
        float c0 = cosb[s*32 + ib],     s0 = sinb[s*32 + ib];
        float c1 = cosb[s*32 + ib + 1], s1 = sinb[s*32 + ib + 1];
        bf16 ko[4];
        ko[0] = (bf16)(e[0]*c0 - e[1]*s0);
        ko[1] = (bf16)(e[0]*s0 + e[1]*c0);
        ko[2] = (bf16)(e[2]*c1 - e[3]*s1);
        ko[3] = (bf16)(e[2]*s1 + e[3]*c1);
        *reinterpret_cast<uint2*>(kpe + (size_t)s * 64 + t * 4) = *reinterpret_cast<uint2*>(ko);
    }

    // ---- q part (in place, cols 0..2047)
    bf16* p = qkv + (size_t)s * QKV_N + t * 8;
    bf16x8 v = *reinterpret_cast<bf16x8*>(p);
    float qf[8];
    #pragma unroll
    for (int j = 0; j < 8; j++) qf[j] = (float)v[j];
    int d0 = (t & 15) * 8;
    if (d0 >= 64) {
        int ib = (d0 - 64) >> 1;
        #pragma unroll
        for (int pr = 0; pr < 4; pr++) {
            float c  = cosb[s * 32 + ib + pr];
            float sn = sinb[s * 32 + ib + pr];
            float xe = qf[pr*2], xo = qf[pr*2 + 1];
            qf[pr*2]     = xe * c - xo * sn;
            qf[pr*2 + 1] = xe * sn + xo * c;
        }
    }
    #pragma unroll
    for (int j = 0; j < 8; j++) v[j] = (bf16)(qf[j] * QSCALE);
    *reinterpret_cast<bf16x8*>(p) = v;
}

// ---------------------------------------------------------------- build Vt[h][128][4096]
__global__ __launch_bounds__(256) void build_vt_kernel(
    const bf16* __restrict__ kvb, bf16* __restrict__ vt) {
    const int LT = 130;
    __shared__ bf16 lt[64 * 130];
    int h  = blockIdx.y;
    int s0 = blockIdx.x * 64;
    int t  = threadIdx.x;
    {
        int row = t >> 2;
        int d0  = (t & 3) * 32;
        const bf16* src = kvb + (size_t)(s0 + row) * 3072 + h * 192 + 64 + d0;
        int4v v0 = *reinterpret_cast<const int4v*>(src);
        int4v v1 = *reinterpret_cast<const int4v*>(src + 8);
        int4v v2 = *reinterpret_cast<const int4v*>(src + 16);
        int4v v3 = *reinterpret_cast<const int4v*>(src + 24);
        int* dst = reinterpret_cast<int*>(&lt[row * LT + d0]);
        int* s0p = reinterpret_cast<int*>(&v0); int* s1p = reinterpret_cast<int*>(&v1);
        int* s2p = reinterpret_cast<int*>(&v2); int* s3p = reinterpret_cast<int*>(&v3);
        #pragma unroll
        for (int j = 0; j < 4; j++) { dst[j] = s0p[j]; dst[4+j] = s1p[j]; dst[8+j] = s2p[j]; dst[12+j] = s3p[j]; }
    }
    __syncthreads();
    int ss = t & 63;
    int db = t >> 6;
    bf16* out = vt + (size_t)h * 128 * 4096 + s0 + ss;
    #pragma unroll
    for (int dd = db; dd < 128; dd += 4)
        out[(size_t)dd * 4096] = lt[ss * LT + dd];
}

// ---------------------------------------------------------------- flash attention (round-11 structure; heavy-first ordering)
// Heavy-first: all heads take tile = 31 - blockIdx.x, so heavy tiles are
// dispatched first and light blocks backfill the tail (round-3 vs-4 A/B:
// heavy-first beat complementary pairing by ~4%).
__global__ __launch_bounds__(256, 2) void attn_kernel(
    const bf16* __restrict__ q,     // [4096][QKV_N]  (roped, *QSCALE, cols 0..2047)
    const bf16* __restrict__ kvb,   // [4096][3072]
    const bf16* __restrict__ kpe,   // [4096][64]
    const bf16* __restrict__ vt,    // [16][128][4096]
    bf16* __restrict__ attn) {      // [4096][2048]
    const int LPS = 72;
    __shared__ __align__(16) bf16 Kl[2][64 * 128];   // 32 KB
    __shared__ __align__(16) bf16 Vl[2][128 * 64];   // 32 KB
    __shared__ __align__(16) bf16 Pl[4][16 * 72];    // 9 KB
    __shared__ __align__(16) float bcast[4][16];     // per-wave row-broadcast

    int h    = blockIdx.y;
    int tile = 31 - (int)blockIdx.x;   // heavy-first for backfill
    int q0   = tile * 128;
    int t  = threadIdx.x;
    int lane = t & 63;
    int w  = t >> 6;
    int l15 = lane & 15;
    int g   = lane >> 4;
    int sw  = l15 & 7;              // read-side XOR swizzle key
    int qrow = q0 + w * 32;

    const bf16* kvbh = kvb + h * 192;
    const bf16* vth  = vt + (size_t)h * 524288;

    bf16x8 qf[2][4];
    #pragma unroll
    for (int mt = 0; mt < 2; mt++) {
        const bf16* qp = q + (size_t)(qrow + mt*16 + l15) * QKV_N + h * 128 + g * 8;
        #pragma unroll
        for (int c = 0; c < 4; c++) qf[mt][c] = *reinterpret_cast<const bf16x8*>(qp + c * 32);
    }

    f32x4 o[2][8] = {};
    float mrow[2], lrow[2];
    #pragma unroll
    for (int mt = 0; mt < 2; mt++) { mrow[mt] = -3e38f; lrow[mt] = 0.f; }

    int nch = (q0 >> 6) + 2;
    int dc  = (q0 >> 6) + (w >> 1);   // this wave's (only) masked chunk

    auto stageK = [&](int jc, int buf) {
        int j0 = jc << 6;
        #pragma unroll
        for (int c = 0; c < 4; c++) {
            int idx = c*256 + w*64 + lane;   // 16B unit index in [0,1024)
            int row = idx >> 4;              // j within chunk
            int u   = (idx & 15) ^ (row & 7);
            const bf16* src = (u < 8)
                ? kvbh + (size_t)(j0 + row) * 3072 + u * 8
                : kpe  + (size_t)(j0 + row) * 64  + (u - 8) * 8;
            __builtin_amdgcn_global_load_lds((gconst_t*)src,
                (lvoid_t*)&Kl[buf][(c*256 + w*64) * 8], 16, 0, 0);
        }
    };
    auto stageV = [&](int jc, int buf) {
        int j0 = jc << 6;
        #pragma unroll
        for (int c = 0; c < 4; c++) {
            int idx = c*256 + w*64 + lane;   // 16B unit index in [0,1024)
            int row = idx >> 3;              // d in [0,128)
            int u   = (idx & 7) ^ (row & 7);
            const bf16* src = vth + (size_t)row * 4096 + j0 + u * 8;
            __builtin_amdgcn_global_load_lds((gconst_t*)src,
                (lvoid_t*)&Vl[buf][(c*256 + w*64) * 8], 16, 0, 0);
        }
    };

    stageK(0, 0); stageV(0, 0);

    for (int jc = 0; jc < nch; ++jc) {
        __syncthreads();                 // implicit vmcnt(0): chunk jc staged, prev reads done
        if (jc + 1 < nch) { stageK(jc + 1, (jc + 1) & 1); stageV(jc + 1, (jc + 1) & 1); }

        if (jc <= dc) {
            int cur = jc & 1;
            int j0  = jc << 6;
            bool masked = (jc == dc);

            // ---- QK^T swapped: S^T[j][i]; lane holds row i=l15, j = j0+16s+g*4+r
            f32x4 sfr[2][4];   // [mt][s]
            #pragma unroll
            for (int s = 0; s < 4; ++s) {
                int krow = s*16 + l15;
                bf16x8 kf[4];
                #pragma unroll
                for (int c = 0; c < 4; ++c)
                    kf[c] = *reinterpret_cast<const bf16x8*>(
                        &Kl[cur][krow*128 + (((c*4 + g) ^ sw) * 8)]);
                #pragma unroll
                for (int mt = 0; mt < 2; ++mt) {
                    f32x4 acc = {};
                    acc = __builtin_amdgcn_mfma_f32_16x16x32_bf16(kf[0], qf[mt][0], acc, 0, 0, 0);
                    acc = __builtin_amdgcn_mfma_f32_16x16x32_bf16(kf[1], qf[mt][1], acc, 0, 0, 0);
                    acc = __builtin_amdgcn_mfma_f32_16x16x32_bf16(kf[2], qf[mt][2], acc, 0, 0, 0);
                    acc = __builtin_amdgcn_mfma_f32_16x16x32_bf16(kf[3], qf[mt][3], acc, 0, 0, 0);
                    sfr[mt][s] = acc;
                }
            }

            // ---- softmax (in-register) + packed P staging, per m-tile
            bf16x8 pf[2][2];
            #pragma unroll
            for (int mt = 0; mt < 2; ++mt) {
                int i = qrow + mt*16 + l15;     // this lane's q-row
                if (masked) {
                    #pragma unroll
                    for (int s = 0; s < 4; ++s)
                        #pragma unroll
                        for (int r = 0; r < 4; ++r) {
                            int j = j0 + s*16 + g*4 + r;
                            if (j > i) sfr[mt][s][r] = -3e38f;
                        }
                }
                float m01 = fmaxf(fmaxf(sfr[mt][0][0], sfr[mt][0][1]),
                                  fmaxf(sfr[mt][0][2], sfr[mt][0][3]));
                float m23 = fmaxf(fmaxf(sfr[mt][1][0], sfr[mt][1][1]),
                                  fmaxf(sfr[mt][1][2], sfr[mt][1][3]));
                float m45 = fmaxf(fmaxf(sfr[mt][2][0], sfr[mt][2][1]),
                                  fmaxf(sfr[mt][2][2], sfr[mt][2][3]));
                float m67 = fmaxf(fmaxf(sfr[mt][3][0], sfr[mt][3][1]),
                                  fmaxf(sfr[mt][3][2], sfr[mt][3][3]));
                float mloc = fmaxf(fmaxf(m01, m23), fmaxf(m45, m67));
                float mx = fmaxf(mloc, __shfl_xor(mloc, 16));
                mx = fmaxf(mx, __shfl_xor(mx, 32));
                bool need = mx > mrow[mt];
                float mnew = fmaxf(mrow[mt], mx);
                float sfac = __builtin_amdgcn_exp2f(mrow[mt] - mnew);
                mrow[mt] = mnew;
                float psum = 0.f;
                #pragma unroll
                for (int s = 0; s < 4; ++s)
                    #pragma unroll
                    for (int r = 0; r < 4; ++r) {
                        float p = __builtin_amdgcn_exp2f(sfr[mt][s][r] - mnew);
                        sfr[mt][s][r] = p;
                        psum += p;
                    }
                lrow[mt] = lrow[mt] * sfac + psum;
                // packed P writes (b64)
                #pragma unroll
                for (int s = 0; s < 4; ++s) {
                    uint2 uu;
                    uu.x = pack2bf(sfr[mt][s][0], sfr[mt][s][1]);
                    uu.y = pack2bf(sfr[mt][s][2], sfr[mt][s][3]);
                    *reinterpret_cast<uint2*>(&Pl[w][l15 * LPS + s*16 + g*4]) = uu;
                }
                // broadcast sfac (per row i) to O-domain lanes
                if (g == 0) bcast[w][l15] = sfac;
                f32x4 sf4 = *reinterpret_cast<const f32x4*>(&bcast[w][g*4]);
                if (__any(need)) {
                    #pragma unroll
                    for (int dt = 0; dt < 8; ++dt)
                        #pragma unroll
                        for (int r = 0; r < 4; ++r) o[mt][dt][r] *= sf4[r];
                }
                pf[mt][0] = *reinterpret_cast<const bf16x8*>(&Pl[w][l15 * LPS + g * 8]);
                pf[mt][1] = *reinterpret_cast<const bf16x8*>(&Pl[w][l15 * LPS + 32 + g * 8]);
            }

            // ---- PV: O[32q][128d] += P[32q][64j] V[64j][128d]
            #pragma unroll
            for (int dt = 0; dt < 8; ++dt) {
                int vrow = dt*16 + l15;
                bf16x8 va = *reinterpret_cast<const bf16x8*>(
                    &Vl[cur][vrow*64 + ((g ^ sw) * 8)]);
                bf16x8 vb = *reinterpret_cast<const bf16x8*>(
                    &Vl[cur][vrow*64 + (((4 + g) ^ sw) * 8)]);
                o[0][dt] = __builtin_amdgcn_mfma_f32_16x16x32_bf16(pf[0][0], va, o[0][dt], 0, 0, 0);
                o[0][dt] = __builtin_amdgcn_mfma_f32_16x16x32_bf16(pf[0][1], vb, o[0][dt], 0, 0, 0);
                o[1][dt] = __builtin_amdgcn_mfma_f32_16x16x32_bf16(pf[1][0], va, o[1][dt], 0, 0, 0);
                o[1][dt] = __builtin_amdgcn_mfma_f32_16x16x32_bf16(pf[1][1], vb, o[1][dt], 0, 0, 0);
            }
        }
    }

    // ---- epilogue: reduce l across g-lanes, broadcast 1/l to O-domain, store
    #pragma unroll
    for (int mt = 0; mt < 2; ++mt) {
        float l = lrow[mt];
        l += __shfl_xor(l, 16);
        l += __shfl_xor(l, 32);
        float linv = __builtin_amdgcn_rcpf(l);
        if (g == 0) bcast[w][l15] = linv;
        f32x4 li4 = *reinterpret_cast<const f32x4*>(&bcast[w][g*4]);
        #pragma unroll
        for (int r = 0; r < 4; ++r) {
            int i = qrow + mt*16 + g*4 + r;
            #pragma unroll
            for (int dt = 0; dt < 8; ++dt)
                attn[(size_t)i * 2048 + h * 128 + dt*16 + l15] = (bf16)(o[mt][dt][r] * li4[r]);
        }
    }
}

// ---------------------------------------------------------------- launch
extern "C" void kernel_launch(void* const* d_in, const int* in_sizes, int n_in,
                              void* d_out, int out_size, void* d_ws, size_t ws_size,
                              hipStream_t stream) {
    const float* x    = (const float*)d_in[0];
    const float* cosb = (const float*)d_in[1];
    const float* sinb = (const float*)d_in[2];
    // d_in[3] = mask (unused: causal, start_pos=0)
    const float* wq   = (const float*)d_in[4];
    const float* wkva = (const float*)d_in[5];
    const float* kvw  = (const float*)d_in[6];
    const float* wkvb = (const float*)d_in[7];
    const float* wo   = (const float*)d_in[8];
    // d_in[9] = start_pos (0)

    char* ws = (char*)d_ws;
    bf16* x_bf    = (bf16*)(ws + 0);          // 16.7MB; later reused as kvnorm, then attn
    bf16* kvnorm  = (bf16*)(ws + 0);
    bf16* attn    = (bf16*)(ws + 0);
    bf16* wq_bf   = (bf16*)(ws + 16777216);   // [2048][2048] bf16
    bf16* wkva_bf = (bf16*)(ws + 25165824);   // [1088][2048] bf16 — contiguous after wq_bf => B=[3136][2048]
    bf16* wkvb_bf = (bf16*)(ws + 29622272);
    bf16* wo_bf   = (bf16*)(ws + 35913728);
    bf16* qkv     = (bf16*)(ws + 44302336);   // [4096][3136] bf16 (q | kv_full)
    bf16* kpe     = (bf16*)(ws + 69992448);
    bf16* kvb     = (bf16*)(ws + 70516736);
    bf16* vt      = (bf16*)(ws + 95682560);
    // total: 112459776 bytes

    convert_all_kernel<<<dim3(2048), dim3(256), 0, stream>>>(
        x, wq, wkva, wkvb, wo, x_bf, wq_bf, wkva_bf, wkvb_bf, wo_bf);

    // merged q + kv_a projection: [4096][3136] = x_bf @ [3136][2048]^T
    gemm256_kernel<256, true><<<dim3(13, 16), dim3(512), 0, stream>>>(x_bf, wq_bf, qkv, 4096, QKV_N, 2048);

    prep_qkv_kernel<<<dim3(4096), dim3(256), 0, stream>>>(qkv, kvw, cosb, sinb, kvnorm, kpe);

    gemm256_kernel<256, true><<<dim3(12, 16), dim3(512), 0, stream>>>(kvnorm, wkvb_bf, kvb, 4096, 3072, 1024);

    build_vt_kernel<<<dim3(64, 16), dim3(256), 0, stream>>>(kvb, vt);

    attn_kernel<<<dim3(32, 16), dim3(256), 0, stream>>>(qkv, kvb, kpe, vt, attn);

    gemm256_kernel<128, false><<<dim3(16, 16), dim3(512), 0, stream>>>(attn, wo_bf, (float*)d_out, 4096, 2048, 2048);
}

// Round 18
// 323.430 us; speedup vs baseline: 1.0961x; 1.0961x over previous
//
#include <hip/hip_runtime.h>

typedef __bf16 bf16;
typedef __attribute__((ext_vector_type(8))) __bf16 bf16x8;
typedef __attribute__((ext_vector_type(2))) __bf16 bf16x2;
typedef __attribute__((ext_vector_type(4))) float f32x4;
typedef __attribute__((ext_vector_type(4))) int int4v;

typedef __attribute__((address_space(1))) const void gconst_t;
typedef __attribute__((address_space(3))) void lvoid_t;

#define SEQ 4096
#define D_IN 2048
#define NHEADS 16
// SCALE * log2(e): attention computed in exp2 domain
#define QSCALE (0.08838834764831843f * 1.4426950408889634f)
#define RMS_EPS 1e-6f
#define QKV_N 3136   // 2048 (q) + 1088 (kv_full)

__device__ inline unsigned pack2bf(float a, float b) {
    bf16x2 t; t[0] = (bf16)a; t[1] = (bf16)b;
    return __builtin_bit_cast(unsigned, t);
}

// ---------------------------------------------------------------- fused conversions
__device__ inline void conv_seg(const float* __restrict__ in, bf16* __restrict__ out,
                                int n, int i0, int stride) {
    for (int i = i0; i < n; i += stride) {
        float4 v = *reinterpret_cast<const float4*>(in + i);
        bf16 o[4];
        o[0] = (bf16)v.x; o[1] = (bf16)v.y; o[2] = (bf16)v.z; o[3] = (bf16)v.w;
        *reinterpret_cast<uint2*>(out + i) = *reinterpret_cast<uint2*>(o);
    }
}

__global__ __launch_bounds__(256) void convert_all_kernel(
    const float* __restrict__ xs,  const float* __restrict__ wqs,
    const float* __restrict__ was, const float* __restrict__ wbs,
    const float* __restrict__ wos,
    bf16* __restrict__ xd, bf16* __restrict__ wqd, bf16* __restrict__ wad,
    bf16* __restrict__ wbd, bf16* __restrict__ wod) {
    int i0 = (blockIdx.x * 256 + threadIdx.x) * 4;
    int stride = gridDim.x * 256 * 4;
    conv_seg(xs,  xd,  4096 * 2048, i0, stride);
    conv_seg(wqs, wqd, 2048 * 2048, i0, stride);
    conv_seg(was, wad, 1088 * 2048, i0, stride);
    conv_seg(wbs, wbd, 3072 * 1024, i0, stride);
    conv_seg(wos, wod, 2048 * 2048, i0, stride);
}

// ---------------------------------------------------------------- 256-wide GEMM, counted-vmcnt 2-barrier schedule
// (round-7/11/14 proven schedule) + T1 XCD-chunked block swizzle
// (round-17 measured: ~11 us on the GEMM chain; bijective since nwg%8==0).
template<int BN, bool BF16_OUT>
__global__ __launch_bounds__(512, 2) void gemm256_kernel(
    const bf16* __restrict__ A, const bf16* __restrict__ B, void* __restrict__ Cout,
    int M, int N, int K) {
    constexpr int CB = BN / 64;      // B stage loads per thread (4 or 2)
    constexpr int NF = BN / 64;      // n-frags per wave (4 or 2)
    constexpr int WC = BN / 4;       // cols per wave
    __shared__ __align__(16) bf16 Al[2][256 * 64];
    __shared__ __align__(16) bf16 Bl[2][BN * 64];

    int t    = threadIdx.x;
    int lane = t & 63;
    int w    = t >> 6;        // 0..7
    int wr   = w >> 2;        // 0..1
    int wc   = w & 3;         // 0..3
    int l15  = lane & 15;
    int g    = lane >> 4;

    // XCD-chunked swizzle (bijective: nwg % 8 == 0 for all launches here)
    int nwg = gridDim.x * gridDim.y;
    int lid = (int)blockIdx.x + (int)gridDim.x * (int)blockIdx.y;
    int cpx = nwg >> 3;
    int nid = (lid & 7) * cpx + (lid >> 3);
    int bx  = nid % (int)gridDim.x;
    int by  = nid / (int)gridDim.x;
    int m0 = by * 256;
    int n0 = bx * BN;

    f32x4 acc[8][NF] = {};

    auto stage = [&](int kt, int buf) {
        int k0 = kt << 6;
        #pragma unroll
        for (int c = 0; c < 4; c++) {           // A: 256 rows x 64 cols
            int idx = c * 512 + t;
            int r = idx >> 3;
            int u = (idx & 7) ^ (r & 7);
            const bf16* ga = A + (size_t)(m0 + r) * K + k0 + u * 8;
            __builtin_amdgcn_global_load_lds((gconst_t*)ga,
                (lvoid_t*)&Al[buf][(c * 512 + w * 64) * 8], 16, 0, 0);
        }
        #pragma unroll
        for (int c = 0; c < CB; c++) {          // B: BN rows x 64 cols
            int idx = c * 512 + t;
            int r = idx >> 3;
            int u = (idx & 7) ^ (r & 7);
            int br = n0 + r; if (br >= N) br = N - 1;
            const bf16* gb = B + (size_t)br * K + k0 + u * 8;
            __builtin_amdgcn_global_load_lds((gconst_t*)gb,
                (lvoid_t*)&Bl[buf][(c * 512 + w * 64) * 8], 16, 0, 0);
        }
    };

    int nt = K >> 6;
    stage(0, 0);
    for (int kt = 0; kt < nt; ++kt) {
        int buf = kt & 1;
        if (kt + 1 < nt) {
            stage(kt + 1, buf ^ 1);
            __builtin_amdgcn_sched_barrier(0);
            if constexpr (BN == 256) asm volatile("s_waitcnt vmcnt(8)" ::: "memory");
            else                     asm volatile("s_waitcnt vmcnt(6)" ::: "memory");
            __builtin_amdgcn_sched_barrier(0);
        } else {
            __builtin_amdgcn_sched_barrier(0);
            asm volatile("s_waitcnt vmcnt(0)" ::: "memory");
            __builtin_amdgcn_sched_barrier(0);
        }
        __builtin_amdgcn_s_barrier();

        #pragma unroll
        for (int ks = 0; ks < 2; ++ks) {
            bf16x8 af[8], bfv[NF];
            #pragma unroll
            for (int mt = 0; mt < 8; mt++) {
                int ra = wr * 128 + mt * 16 + l15;
                int u = (ks * 4 + g) ^ (ra & 7);
                af[mt] = *reinterpret_cast<const bf16x8*>(&Al[buf][ra * 64 + u * 8]);
            }
            #pragma unroll
            for (int nf = 0; nf < NF; nf++) {
                int rb = wc * WC + nf * 16 + l15;
                int u = (ks * 4 + g) ^ (rb & 7);
                bfv[nf] = *reinterpret_cast<const bf16x8*>(&Bl[buf][rb * 64 + u * 8]);
            }
            __builtin_amdgcn_s_setprio(1);
            #pragma unroll
            for (int mt = 0; mt < 8; mt++)
                #pragma unroll
                for (int nf = 0; nf < NF; nf++)
                    acc[mt][nf] = __builtin_amdgcn_mfma_f32_16x16x32_bf16(af[mt], bfv[nf], acc[mt][nf], 0, 0, 0);
            __builtin_amdgcn_s_setprio(0);
        }
        __builtin_amdgcn_s_barrier();
    }

    #pragma unroll
    for (int mt = 0; mt < 8; mt++) {
        #pragma unroll
        for (int nf = 0; nf < NF; nf++) {
            int col = n0 + wc * WC + nf * 16 + l15;
            if (col < N) {
                #pragma unroll
                for (int r = 0; r < 4; r++) {
                    int row = m0 + wr * 128 + mt * 16 + g * 4 + r;
                    if (BF16_OUT)
                        ((bf16*)Cout)[(size_t)row * N + col] = (bf16)acc[mt][nf][r];
                    else
                        ((float*)Cout)[(size_t)row * N + col] = acc[mt][nf][r];
                }
            }
        }
    }
}

// ---------------------------------------------------------------- fused q+kv prep
__global__ __launch_bounds__(256) void prep_qkv_kernel(
    bf16* __restrict__ qkv, const float* __restrict__ w,
    const float* __restrict__ cosb, const float* __restrict__ sinb,
    bf16* __restrict__ kvnorm, bf16* __restrict__ kpe) {
    __shared__ float red[4];
    int s = blockIdx.x;
    int t = threadIdx.x;

    // ---- kv part
    const bf16* src = qkv + (size_t)s * QKV_N + 2048;
    float f[4];
    {
        uint2 raw = *reinterpret_cast<const uint2*>(src + t * 4);
        bf16* vb = reinterpret_cast<bf16*>(&raw);
        float ss = 0.f;
        #pragma unroll
        for (int j = 0; j < 4; j++) { f[j] = (float)vb[j]; ss += f[j] * f[j]; }
        #pragma unroll
        for (int m = 1; m < 64; m <<= 1) ss += __shfl_xor(ss, m);
        if ((t & 63) == 0) red[t >> 6] = ss;
    }
    __syncthreads();
    float tot = red[0] + red[1] + red[2] + red[3];
    float rms = rsqrtf(tot * (1.0f / 1024.0f) + RMS_EPS);
    bf16 o[4];
    #pragma unroll
    for (int j = 0; j < 4; j++) o[j] = (bf16)(f[j] * rms * w[t*4 + j]);
    *reinterpret_cast<uint2*>(kvnorm + (size_t)s * 1024 + t * 4) = *reinterpret_cast<uint2*>(o);
    if (t < 16) {
        float e[4];
        #pragma unroll
        for (int j = 0; j < 4; j++) e[j] = (float)src[1024 + t*4 + j];
        int ib = t * 2;
        float c0 = cosb[s*32 + ib],     s0 = sinb[s*32 + ib];
        float c1 = cosb[s*32 + ib + 1], s1 = sinb[s*32 + ib + 1];
        bf16 ko[4];
        ko[0] = (bf16)(e[0]*c0 - e[1]*s0);
        ko[1] = (bf16)(e[0]*s0 + e[1]*c0);
        ko[2] = (bf16)(e[2]*c1 - e[3]*s1);
        ko[3] = (bf16)(e[2]*s1 + e[3]*c1);
        *reinterpret_cast<uint2*>(kpe + (size_t)s * 64 + t * 4) = *reinterpret_cast<uint2*>(ko);
    }

    // ---- q part (in place, cols 0..2047)
    bf16* p = qkv + (size_t)s * QKV_N + t * 8;
    bf16x8 v = *reinterpret_cast<bf16x8*>(p);
    float qf[8];
    #pragma unroll
    for (int j = 0; j < 8; j++) qf[j] = (float)v[j];
    int d0 = (t & 15) * 8;
    if (d0 >= 64) {
        int ib = (d0 - 64) >> 1;
        #pragma unroll
        for (int pr = 0; pr < 4; pr++) {
            float c  = cosb[s * 32 + ib + pr];
            float sn = sinb[s * 32 + ib + pr];
            float xe = qf[pr*2], xo = qf[pr*2 + 1];
            qf[pr*2]     = xe * c - xo * sn;
            qf[pr*2 + 1] = xe * sn + xo * c;
        }
    }
    #pragma unroll
    for (int j = 0; j < 8; j++) v[j] = (bf16)(qf[j] * QSCALE);
    *reinterpret_cast<bf16x8*>(p) = v;
}

// ---------------------------------------------------------------- build Vt[h][128][4096]
__global__ __launch_bounds__(256) void build_vt_kernel(
    const bf16* __restrict__ kvb, bf16* __restrict__ vt) {
    const int LT = 130;
    __shared__ bf16 lt[64 * 130];
    int h  = blockIdx.y;
    int s0 = blockIdx.x * 64;
    int t  = threadIdx.x;
    {
        int row = t >> 2;
        int d0  = (t & 3) * 32;
        const bf16* src = kvb + (size_t)(s0 + row) * 3072 + h * 192 + 64 + d0;
        int4v v0 = *reinterpret_cast<const int4v*>(src);
        int4v v1 = *reinterpret_cast<const int4v*>(src + 8);
        int4v v2 = *reinterpret_cast<const int4v*>(src + 16);
        int4v v3 = *reinterpret_cast<const int4v*>(src + 24);
        int* dst = reinterpret_cast<int*>(&lt[row * LT + d0]);
        int* s0p = reinterpret_cast<int*>(&v0); int* s1p = reinterpret_cast<int*>(&v1);
        int* s2p = reinterpret_cast<int*>(&v2); int* s3p = reinterpret_cast<int*>(&v3);
        #pragma unroll
        for (int j = 0; j < 4; j++) { dst[j] = s0p[j]; dst[4+j] = s1p[j]; dst[8+j] = s2p[j]; dst[12+j] = s3p[j]; }
    }
    __syncthreads();
    int ss = t & 63;
    int db = t >> 6;
    bf16* out = vt + (size_t)h * 128 * 4096 + s0 + ss;
    #pragma unroll
    for (int dd = db; dd < 128; dd += 4)
        out[(size_t)dd * 4096] = lt[ss * LT + dd];
}

// ---------------------------------------------------------------- flash attention (round-16 green version: complementary pairing)
__global__ __launch_bounds__(256, 2) void attn_kernel(
    const bf16* __restrict__ q,     // [4096][QKV_N]  (roped, *QSCALE, cols 0..2047)
    const bf16* __restrict__ kvb,   // [4096][3072]
    const bf16* __restrict__ kpe,   // [4096][64]
    const bf16* __restrict__ vt,    // [16][128][4096]
    bf16* __restrict__ attn) {      // [4096][2048]
    const int LPS = 72;
    __shared__ __align__(16) bf16 Kl[2][64 * 128];   // 32 KB
    __shared__ __align__(16) bf16 Vl[2][128 * 64];   // 32 KB
    __shared__ __align__(16) bf16 Pl[4][16 * 72];    // 9 KB
    __shared__ __align__(16) float bcast[4][16];     // per-wave row-broadcast

    int h    = blockIdx.y;
    int tile = (h < 8) ? (31 - (int)blockIdx.x) : (int)blockIdx.x;
    int q0   = tile * 128;
    int t  = threadIdx.x;
    int lane = t & 63;
    int w  = t >> 6;
    int l15 = lane & 15;
    int g   = lane >> 4;
    int sw  = l15 & 7;              // read-side XOR swizzle key
    int qrow = q0 + w * 32;

    const bf16* kvbh = kvb + h * 192;
    const bf16* vth  = vt + (size_t)h * 524288;

    bf16x8 qf[2][4];
    #pragma unroll
    for (int mt = 0; mt < 2; mt++) {
        const bf16* qp = q + (size_t)(qrow + mt*16 + l15) * QKV_N + h * 128 + g * 8;
        #pragma unroll
        for (int c = 0; c < 4; c++) qf[mt][c] = *reinterpret_cast<const bf16x8*>(qp + c * 32);
    }

    f32x4 o[2][8] = {};
    float mrow[2], lrow[2];
    #pragma unroll
    for (int mt = 0; mt < 2; mt++) { mrow[mt] = -3e38f; lrow[mt] = 0.f; }

    int nch = (q0 >> 6) + 2;
    int dc  = (q0 >> 6) + (w >> 1);   // this wave's (only) masked chunk

    auto stageK = [&](int jc, int buf) {
        int j0 = jc << 6;
        #pragma unroll
        for (int c = 0; c < 4; c++) {
            int idx = c*256 + w*64 + lane;   // 16B unit index in [0,1024)
            int row = idx >> 4;              // j within chunk
            int u   = (idx & 15) ^ (row & 7);
            const bf16* src = (u < 8)
                ? kvbh + (size_t)(j0 + row) * 3072 + u * 8
                : kpe  + (size_t)(j0 + row) * 64  + (u - 8) * 8;
            __builtin_amdgcn_global_load_lds((gconst_t*)src,
                (lvoid_t*)&Kl[buf][(c*256 + w*64) * 8], 16, 0, 0);
        }
    };
    auto stageV = [&](int jc, int buf) {
        int j0 = jc << 6;
        #pragma unroll
        for (int c = 0; c < 4; c++) {
            int idx = c*256 + w*64 + lane;   // 16B unit index in [0,1024)
            int row = idx >> 3;              // d in [0,128)
            int u   = (idx & 7) ^ (row & 7);
            const bf16* src = vth + (size_t)row * 4096 + j0 + u * 8;
            __builtin_amdgcn_global_load_lds((gconst_t*)src,
                (lvoid_t*)&Vl[buf][(c*256 + w*64) * 8], 16, 0, 0);
        }
    };

    stageK(0, 0); stageV(0, 0);

    for (int jc = 0; jc < nch; ++jc) {
        __syncthreads();                 // implicit vmcnt(0): chunk jc staged, prev reads done
        if (jc + 1 < nch) { stageK(jc + 1, (jc + 1) & 1); stageV(jc + 1, (jc + 1) & 1); }

        if (jc <= dc) {
            int cur = jc & 1;
            int j0  = jc << 6;
            bool masked = (jc == dc);

            // ---- QK^T swapped: S^T[j][i]; lane holds row i=l15, j = j0+16s+g*4+r
            f32x4 sfr[2][4];   // [mt][s]
            #pragma unroll
            for (int s = 0; s < 4; ++s) {
                int krow = s*16 + l15;
                bf16x8 kf[4];
                #pragma unroll
                for (int c = 0; c < 4; ++c)
                    kf[c] = *reinterpret_cast<const bf16x8*>(
                        &Kl[cur][krow*128 + (((c*4 + g) ^ sw) * 8)]);
                #pragma unroll
                for (int mt = 0; mt < 2; ++mt) {
                    f32x4 acc = {};
                    acc = __builtin_amdgcn_mfma_f32_16x16x32_bf16(kf[0], qf[mt][0], acc, 0, 0, 0);
                    acc = __builtin_amdgcn_mfma_f32_16x16x32_bf16(kf[1], qf[mt][1], acc, 0, 0, 0);
                    acc = __builtin_amdgcn_mfma_f32_16x16x32_bf16(kf[2], qf[mt][2], acc, 0, 0, 0);
                    acc = __builtin_amdgcn_mfma_f32_16x16x32_bf16(kf[3], qf[mt][3], acc, 0, 0, 0);
                    sfr[mt][s] = acc;
                }
            }

            // ---- softmax (in-register) + packed P staging, per m-tile
            bf16x8 pf[2][2];
            #pragma unroll
            for (int mt = 0; mt < 2; ++mt) {
                int i = qrow + mt*16 + l15;     // this lane's q-row
                if (masked) {
                    #pragma unroll
                    for (int s = 0; s < 4; ++s)
                        #pragma unroll
                        for (int r = 0; r < 4; ++r) {
                            int j = j0 + s*16 + g*4 + r;
                            if (j > i) sfr[mt][s][r] = -3e38f;
                        }
                }
                float m01 = fmaxf(fmaxf(sfr[mt][0][0], sfr[mt][0][1]),
                                  fmaxf(sfr[mt][0][2], sfr[mt][0][3]));
                float m23 = fmaxf(fmaxf(sfr[mt][1][0], sfr[mt][1][1]),
                                  fmaxf(sfr[mt][1][2], sfr[mt][1][3]));
                float m45 = fmaxf(fmaxf(sfr[mt][2][0], sfr[mt][2][1]),
                                  fmaxf(sfr[mt][2][2], sfr[mt][2][3]));
                float m67 = fmaxf(fmaxf(sfr[mt][3][0], sfr[mt][3][1]),
                                  fmaxf(sfr[mt][3][2], sfr[mt][3][3]));
                float mloc = fmaxf(fmaxf(m01, m23), fmaxf(m45, m67));
                float mx = fmaxf(mloc, __shfl_xor(mloc, 16));
                mx = fmaxf(mx, __shfl_xor(mx, 32));
                bool need = mx > mrow[mt];
                float mnew = fmaxf(mrow[mt], mx);
                float sfac = __builtin_amdgcn_exp2f(mrow[mt] - mnew);
                mrow[mt] = mnew;
                float psum = 0.f;
                #pragma unroll
                for (int s = 0; s < 4; ++s)
                    #pragma unroll
                    for (int r = 0; r < 4; ++r) {
                        float p = __builtin_amdgcn_exp2f(sfr[mt][s][r] - mnew);
                        sfr[mt][s][r] = p;
                        psum += p;
                    }
                lrow[mt] = lrow[mt] * sfac + psum;
                // packed P writes (b64)
                #pragma unroll
                for (int s = 0; s < 4; ++s) {
                    uint2 uu;
                    uu.x = pack2bf(sfr[mt][s][0], sfr[mt][s][1]);
                    uu.y = pack2bf(sfr[mt][s][2], sfr[mt][s][3]);
                    *reinterpret_cast<uint2*>(&Pl[w][l15 * LPS + s*16 + g*4]) = uu;
                }
                // broadcast sfac (per row i) to O-domain lanes
                if (g == 0) bcast[w][l15] = sfac;
                f32x4 sf4 = *reinterpret_cast<const f32x4*>(&bcast[w][g*4]);
                if (__any(need)) {
                    #pragma unroll
                    for (int dt = 0; dt < 8; ++dt)
                        #pragma unroll
                        for (int r = 0; r < 4; ++r) o[mt][dt][r] *= sf4[r];
                }
                pf[mt][0] = *reinterpret_cast<const bf16x8*>(&Pl[w][l15 * LPS + g * 8]);
                pf[mt][1] = *reinterpret_cast<const bf16x8*>(&Pl[w][l15 * LPS + 32 + g * 8]);
            }

            // ---- PV: O[32q][128d] += P[32q][64j] V[64j][128d]
            #pragma unroll
            for (int dt = 0; dt < 8; ++dt) {
                int vrow = dt*16 + l15;
                bf16x8 va = *reinterpret_cast<const bf16x8*>(
                    &Vl[cur][vrow*64 + ((g ^ sw) * 8)]);
                bf16x8 vb = *reinterpret_cast<const bf16x8*>(
                    &Vl[cur][vrow*64 + (((4 + g) ^ sw) * 8)]);
                o[0][dt] = __builtin_amdgcn_mfma_f32_16x16x32_bf16(pf[0][0], va, o[0][dt], 0, 0, 0);
                o[0][dt] = __builtin_amdgcn_mfma_f32_16x16x32_bf16(pf[0][1], vb, o[0][dt], 0, 0, 0);
                o[1][dt] = __builtin_amdgcn_mfma_f32_16x16x32_bf16(pf[1][0], va, o[1][dt], 0, 0, 0);
                o[1][dt] = __builtin_amdgcn_mfma_f32_16x16x32_bf16(pf[1][1], vb, o[1][dt], 0, 0, 0);
            }
        }
    }

    // ---- epilogue: reduce l across g-lanes, broadcast 1/l to O-domain, store
    #pragma unroll
    for (int mt = 0; mt < 2; ++mt) {
        float l = lrow[mt];
        l += __shfl_xor(l, 16);
        l += __shfl_xor(l, 32);
        float linv = __builtin_amdgcn_rcpf(l);
        if (g == 0) bcast[w][l15] = linv;
        f32x4 li4 = *reinterpret_cast<const f32x4*>(&bcast[w][g*4]);
        #pragma unroll
        for (int r = 0; r < 4; ++r) {
            int i = qrow + mt*16 + g*4 + r;
            #pragma unroll
            for (int dt = 0; dt < 8; ++dt)
                attn[(size_t)i * 2048 + h * 128 + dt*16 + l15] = (bf16)(o[mt][dt][r] * li4[r]);
        }
    }
}

// ---------------------------------------------------------------- launch
extern "C" void kernel_launch(void* const* d_in, const int* in_sizes, int n_in,
                              void* d_out, int out_size, void* d_ws, size_t ws_size,
                              hipStream_t stream) {
    const float* x    = (const float*)d_in[0];
    const float* cosb = (const float*)d_in[1];
    const float* sinb = (const float*)d_in[2];
    // d_in[3] = mask (unused: causal, start_pos=0)
    const float* wq   = (const float*)d_in[4];
    const float* wkva = (const float*)d_in[5];
    const float* kvw  = (const float*)d_in[6];
    const float* wkvb = (const float*)d_in[7];
    const float* wo   = (const float*)d_in[8];
    // d_in[9] = start_pos (0)

    char* ws = (char*)d_ws;
    bf16* x_bf    = (bf16*)(ws + 0);          // 16.7MB; later reused as kvnorm, then attn
    bf16* kvnorm  = (bf16*)(ws + 0);
    bf16* attn    = (bf16*)(ws + 0);
    bf16* wq_bf   = (bf16*)(ws + 16777216);   // [2048][2048] bf16
    bf16* wkva_bf = (bf16*)(ws + 25165824);   // [1088][2048] bf16 — contiguous after wq_bf => B=[3136][2048]
    bf16* wkvb_bf = (bf16*)(ws + 29622272);
    bf16* wo_bf   = (bf16*)(ws + 35913728);
    bf16* qkv     = (bf16*)(ws + 44302336);   // [4096][3136] bf16 (q | kv_full)
    bf16* kpe     = (bf16*)(ws + 69992448);
    bf16* kvb     = (bf16*)(ws + 70516736);
    bf16* vt      = (bf16*)(ws + 95682560);
    // total: 112459776 bytes

    convert_all_kernel<<<dim3(2048), dim3(256), 0, stream>>>(
        x, wq, wkva, wkvb, wo, x_bf, wq_bf, wkva_bf, wkvb_bf, wo_bf);

    // merged q + kv_a projection: [4096][3136] = x_bf @ [3136][2048]^T
    gemm256_kernel<256, true><<<dim3(13, 16), dim3(512), 0, stream>>>(x_bf, wq_bf, qkv, 4096, QKV_N, 2048);

    prep_qkv_kernel<<<dim3(4096), dim3(256), 0, stream>>>(qkv, kvw, cosb, sinb, kvnorm, kpe);

    gemm256_kernel<256, true><<<dim3(12, 16), dim3(512), 0, stream>>>(kvnorm, wkvb_bf, kvb, 4096, 3072, 1024);

    build_vt_kernel<<<dim3(64, 16), dim3(256), 0, stream>>>(kvb, vt);

    attn_kernel<<<dim3(32, 16), dim3(256), 0, stream>>>(qkv, kvb, kpe, vt, attn);

    gemm256_kernel<128, false><<<dim3(16, 16), dim3(512), 0, stream>>>(attn, wo_bf, (float*)d_out, 4096, 2048, 2048);
}

// Round 19
// 320.143 us; speedup vs baseline: 1.1073x; 1.0103x over previous
//
#include <hip/hip_runtime.h>

typedef __bf16 bf16;
typedef __attribute__((ext_vector_type(8))) __bf16 bf16x8;
typedef __attribute__((ext_vector_type(2))) __bf16 bf16x2;
typedef __attribute__((ext_vector_type(4))) float f32x4;
typedef __attribute__((ext_vector_type(4))) int int4v;

typedef __attribute__((address_space(1))) const void gconst_t;
typedef __attribute__((address_space(3))) void lvoid_t;

#define SEQ 4096
#define D_IN 2048
#define NHEADS 16
// SCALE * log2(e): attention computed in exp2 domain
#define QSCALE (0.08838834764831843f * 1.4426950408889634f)
#define RMS_EPS 1e-6f
#define QKV_N 3136   // 2048 (q) + 1088 (kv_full)

__device__ inline unsigned pack2bf(float a, float b) {
    bf16x2 t; t[0] = (bf16)a; t[1] = (bf16)b;
    return __builtin_bit_cast(unsigned, t);
}

// ---------------------------------------------------------------- fused conversions
__device__ inline void conv_seg(const float* __restrict__ in, bf16* __restrict__ out,
                                int n, int i0, int stride) {
    for (int i = i0; i < n; i += stride) {
        float4 v = *reinterpret_cast<const float4*>(in + i);
        bf16 o[4];
        o[0] = (bf16)v.x; o[1] = (bf16)v.y; o[2] = (bf16)v.z; o[3] = (bf16)v.w;
        *reinterpret_cast<uint2*>(out + i) = *reinterpret_cast<uint2*>(o);
    }
}

__global__ __launch_bounds__(256) void convert_all_kernel(
    const float* __restrict__ xs,  const float* __restrict__ wqs,
    const float* __restrict__ was, const float* __restrict__ wbs,
    const float* __restrict__ wos,
    bf16* __restrict__ xd, bf16* __restrict__ wqd, bf16* __restrict__ wad,
    bf16* __restrict__ wbd, bf16* __restrict__ wod) {
    int i0 = (blockIdx.x * 256 + threadIdx.x) * 4;
    int stride = gridDim.x * 256 * 4;
    conv_seg(xs,  xd,  4096 * 2048, i0, stride);
    conv_seg(wqs, wqd, 2048 * 2048, i0, stride);
    conv_seg(was, wad, 1088 * 2048, i0, stride);
    conv_seg(wbs, wbd, 3072 * 1024, i0, stride);
    conv_seg(wos, wod, 2048 * 2048, i0, stride);
}

// ---------------------------------------------------------------- 256-wide GEMM, counted-vmcnt 2-barrier schedule
// (round-7/11/14 proven schedule) + T1 XCD-chunked block swizzle
// (round-17/18 measured: ~9-11 us on the GEMM chain).
template<int BN, bool BF16_OUT>
__global__ __launch_bounds__(512, 2) void gemm256_kernel(
    const bf16* __restrict__ A, const bf16* __restrict__ B, void* __restrict__ Cout,
    int M, int N, int K) {
    constexpr int CB = BN / 64;      // B stage loads per thread (4 or 2)
    constexpr int NF = BN / 64;      // n-frags per wave (4 or 2)
    constexpr int WC = BN / 4;       // cols per wave
    __shared__ __align__(16) bf16 Al[2][256 * 64];
    __shared__ __align__(16) bf16 Bl[2][BN * 64];

    int t    = threadIdx.x;
    int lane = t & 63;
    int w    = t >> 6;        // 0..7
    int wr   = w >> 2;        // 0..1
    int wc   = w & 3;         // 0..3
    int l15  = lane & 15;
    int g    = lane >> 4;

    // XCD-chunked swizzle (bijective: nwg % 8 == 0 for all launches here)
    int nwg = gridDim.x * gridDim.y;
    int lid = (int)blockIdx.x + (int)gridDim.x * (int)blockIdx.y;
    int cpx = nwg >> 3;
    int nid = (lid & 7) * cpx + (lid >> 3);
    int bx  = nid % (int)gridDim.x;
    int by  = nid / (int)gridDim.x;
    int m0 = by * 256;
    int n0 = bx * BN;

    f32x4 acc[8][NF] = {};

    auto stage = [&](int kt, int buf) {
        int k0 = kt << 6;
        #pragma unroll
        for (int c = 0; c < 4; c++) {           // A: 256 rows x 64 cols
            int idx = c * 512 + t;
            int r = idx >> 3;
            int u = (idx & 7) ^ (r & 7);
            const bf16* ga = A + (size_t)(m0 + r) * K + k0 + u * 8;
            __builtin_amdgcn_global_load_lds((gconst_t*)ga,
                (lvoid_t*)&Al[buf][(c * 512 + w * 64) * 8], 16, 0, 0);
        }
        #pragma unroll
        for (int c = 0; c < CB; c++) {          // B: BN rows x 64 cols
            int idx = c * 512 + t;
            int r = idx >> 3;
            int u = (idx & 7) ^ (r & 7);
            int br = n0 + r; if (br >= N) br = N - 1;
            const bf16* gb = B + (size_t)br * K + k0 + u * 8;
            __builtin_amdgcn_global_load_lds((gconst_t*)gb,
                (lvoid_t*)&Bl[buf][(c * 512 + w * 64) * 8], 16, 0, 0);
        }
    };

    int nt = K >> 6;
    stage(0, 0);
    for (int kt = 0; kt < nt; ++kt) {
        int buf = kt & 1;
        if (kt + 1 < nt) {
            stage(kt + 1, buf ^ 1);
            __builtin_amdgcn_sched_barrier(0);
            if constexpr (BN == 256) asm volatile("s_waitcnt vmcnt(8)" ::: "memory");
            else                     asm volatile("s_waitcnt vmcnt(6)" ::: "memory");
            __builtin_amdgcn_sched_barrier(0);
        } else {
            __builtin_amdgcn_sched_barrier(0);
            asm volatile("s_waitcnt vmcnt(0)" ::: "memory");
            __builtin_amdgcn_sched_barrier(0);
        }
        __builtin_amdgcn_s_barrier();

        #pragma unroll
        for (int ks = 0; ks < 2; ++ks) {
            bf16x8 af[8], bfv[NF];
            #pragma unroll
            for (int mt = 0; mt < 8; mt++) {
                int ra = wr * 128 + mt * 16 + l15;
                int u = (ks * 4 + g) ^ (ra & 7);
                af[mt] = *reinterpret_cast<const bf16x8*>(&Al[buf][ra * 64 + u * 8]);
            }
            #pragma unroll
            for (int nf = 0; nf < NF; nf++) {
                int rb = wc * WC + nf * 16 + l15;
                int u = (ks * 4 + g) ^ (rb & 7);
                bfv[nf] = *reinterpret_cast<const bf16x8*>(&Bl[buf][rb * 64 + u * 8]);
            }
            __builtin_amdgcn_s_setprio(1);
            #pragma unroll
            for (int mt = 0; mt < 8; mt++)
                #pragma unroll
                for (int nf = 0; nf < NF; nf++)
                    acc[mt][nf] = __builtin_amdgcn_mfma_f32_16x16x32_bf16(af[mt], bfv[nf], acc[mt][nf], 0, 0, 0);
            __builtin_amdgcn_s_setprio(0);
        }
        __builtin_amdgcn_s_barrier();
    }

    #pragma unroll
    for (int mt = 0; mt < 8; mt++) {
        #pragma unroll
        for (int nf = 0; nf < NF; nf++) {
            int col = n0 + wc * WC + nf * 16 + l15;
            if (col < N) {
                #pragma unroll
                for (int r = 0; r < 4; r++) {
                    int row = m0 + wr * 128 + mt * 16 + g * 4 + r;
                    if (BF16_OUT)
                        ((bf16*)Cout)[(size_t)row * N + col] = (bf16)acc[mt][nf][r];
                    else
                        ((float*)Cout)[(size_t)row * N + col] = acc[mt][nf][r];
                }
            }
        }
    }
}

// ---------------------------------------------------------------- fused q+kv prep
__global__ __launch_bounds__(256) void prep_qkv_kernel(
    bf16* __restrict__ qkv, const float* __restrict__ w,
    const float* __restrict__ cosb, const float* __restrict__ sinb,
    bf16* __restrict__ kvnorm, bf16* __restrict__ kpe) {
    __shared__ float red[4];
    int s = blockIdx.x;
    int t = threadIdx.x;

    // ---- kv part
    const bf16* src = qkv + (size_t)s * QKV_N + 2048;
    float f[4];
    {
        uint2 raw = *reinterpret_cast<const uint2*>(src + t * 4);
        bf16* vb = reinterpret_cast<bf16*>(&raw);
        float ss = 0.f;
        #pragma unroll
        for (int j = 0; j < 4; j++) { f[j] = (float)vb[j]; ss += f[j] * f[j]; }
        #pragma unroll
        for (int m = 1; m < 64; m <<= 1) ss += __shfl_xor(ss, m);
        if ((t & 63) == 0) red[t >> 6] = ss;
    }
    __syncthreads();
    float tot = red[0] + red[1] + red[2] + red[3];
    float rms = rsqrtf(tot * (1.0f / 1024.0f) + RMS_EPS);
    bf16 o[4];
    #pragma unroll
    for (int j = 0; j < 4; j++) o[j] = (bf16)(f[j] * rms * w[t*4 + j]);
    *reinterpret_cast<uint2*>(kvnorm + (size_t)s * 1024 + t * 4) = *reinterpret_cast<uint2*>(o);
    if (t < 16) {
        float e[4];
        #pragma unroll
        for (int j = 0; j < 4; j++) e[j] = (float)src[1024 + t*4 + j];
        int ib = t * 2;
        float c0 = cosb[s*32 + ib],     s0 = sinb[s*32 + ib];
        float c1 = cosb[s*32 + ib + 1], s1 = sinb[s*32 + ib + 1];
        bf16 ko[4];
        ko[0] = (bf16)(e[0]*c0 - e[1]*s0);
        ko[1] = (bf16)(e[0]*s0 + e[1]*c0);
        ko[2] = (bf16)(e[2]*c1 - e[3]*s1);
        ko[3] = (bf16)(e[2]*s1 + e[3]*c1);
        *reinterpret_cast<uint2*>(kpe + (size_t)s * 64 + t * 4) = *reinterpret_cast<uint2*>(ko);
    }

    // ---- q part (in place, cols 0..2047)
    bf16* p = qkv + (size_t)s * QKV_N + t * 8;
    bf16x8 v = *reinterpret_cast<bf16x8*>(p);
    float qf[8];
    #pragma unroll
    for (int j = 0; j < 8; j++) qf[j] = (float)v[j];
    int d0 = (t & 15) * 8;
    if (d0 >= 64) {
        int ib = (d0 - 64) >> 1;
        #pragma unroll
        for (int pr = 0; pr < 4; pr++) {
            float c  = cosb[s * 32 + ib + pr];
            float sn = sinb[s * 32 + ib + pr];
            float xe = qf[pr*2], xo = qf[pr*2 + 1];
            qf[pr*2]     = xe * c - xo * sn;
            qf[pr*2 + 1] = xe * sn + xo * c;
        }
    }
    #pragma unroll
    for (int j = 0; j < 8; j++) v[j] = (bf16)(qf[j] * QSCALE);
    *reinterpret_cast<bf16x8*>(p) = v;
}

// ---------------------------------------------------------------- build Vt[h][128][4096]
__global__ __launch_bounds__(256) void build_vt_kernel(
    const bf16* __restrict__ kvb, bf16* __restrict__ vt) {
    const int LT = 130;
    __shared__ bf16 lt[64 * 130];
    int h  = blockIdx.y;
    int s0 = blockIdx.x * 64;
    int t  = threadIdx.x;
    {
        int row = t >> 2;
        int d0  = (t & 3) * 32;
        const bf16* src = kvb + (size_t)(s0 + row) * 3072 + h * 192 + 64 + d0;
        int4v v0 = *reinterpret_cast<const int4v*>(src);
        int4v v1 = *reinterpret_cast<const int4v*>(src + 8);
        int4v v2 = *reinterpret_cast<const int4v*>(src + 16);
        int4v v3 = *reinterpret_cast<const int4v*>(src + 24);
        int* dst = reinterpret_cast<int*>(&lt[row * LT + d0]);
        int* s0p = reinterpret_cast<int*>(&v0); int* s1p = reinterpret_cast<int*>(&v1);
        int* s2p = reinterpret_cast<int*>(&v2); int* s3p = reinterpret_cast<int*>(&v3);
        #pragma unroll
        for (int j = 0; j < 4; j++) { dst[j] = s0p[j]; dst[4+j] = s1p[j]; dst[8+j] = s2p[j]; dst[12+j] = s3p[j]; }
    }
    __syncthreads();
    int ss = t & 63;
    int db = t >> 6;
    bf16* out = vt + (size_t)h * 128 * 4096 + s0 + ss;
    #pragma unroll
    for (int dd = db; dd < 128; dd += 4)
        out[(size_t)dd * 4096] = lt[ss * LT + dd];
}

// ---------------------------------------------------------------- flash attention
// Round-18 green structure + T1 XCD-chunked grid remap:
//   slot L -> nid=(L&7)*64+(L>>3); bx=nid&31, h=nid>>5 -> XCD k owns heads
//   2k,2k+1 entirely (K/V/vt panels fetched ~once per L2 instead of 8x).
// Complementary pairing preserved in the remapped domain: co-resident slots
// (L, L+256) -> (bx,h even),(bx,h odd); tile = (h&1)? bx : 31-bx gives
// constant per-CU pair work (31 chunks), same invariant as round 18.
__global__ __launch_bounds__(256, 2) void attn_kernel(
    const bf16* __restrict__ q,     // [4096][QKV_N]  (roped, *QSCALE, cols 0..2047)
    const bf16* __restrict__ kvb,   // [4096][3072]
    const bf16* __restrict__ kpe,   // [4096][64]
    const bf16* __restrict__ vt,    // [16][128][4096]
    bf16* __restrict__ attn) {      // [4096][2048]
    const int LPS = 72;
    __shared__ __align__(16) bf16 Kl[2][64 * 128];   // 32 KB
    __shared__ __align__(16) bf16 Vl[2][128 * 64];   // 32 KB
    __shared__ __align__(16) bf16 Pl[4][16 * 72];    // 9 KB
    __shared__ __align__(16) float bcast[4][16];     // per-wave row-broadcast

    int L    = (int)blockIdx.x + 32 * (int)blockIdx.y;   // physical slot
    int nid  = (L & 7) * 64 + (L >> 3);                  // XCD-chunked remap
    int bx   = nid & 31;
    int h    = nid >> 5;
    int tile = (h & 1) ? bx : (31 - bx);
    int q0   = tile * 128;
    int t  = threadIdx.x;
    int lane = t & 63;
    int w  = t >> 6;
    int l15 = lane & 15;
    int g   = lane >> 4;
    int sw  = l15 & 7;              // read-side XOR swizzle key
    int qrow = q0 + w * 32;

    const bf16* kvbh = kvb + h * 192;
    const bf16* vth  = vt + (size_t)h * 524288;

    bf16x8 qf[2][4];
    #pragma unroll
    for (int mt = 0; mt < 2; mt++) {
        const bf16* qp = q + (size_t)(qrow + mt*16 + l15) * QKV_N + h * 128 + g * 8;
        #pragma unroll
        for (int c = 0; c < 4; c++) qf[mt][c] = *reinterpret_cast<const bf16x8*>(qp + c * 32);
    }

    f32x4 o[2][8] = {};
    float mrow[2], lrow[2];
    #pragma unroll
    for (int mt = 0; mt < 2; mt++) { mrow[mt] = -3e38f; lrow[mt] = 0.f; }

    int nch = (q0 >> 6) + 2;
    int dc  = (q0 >> 6) + (w >> 1);   // this wave's (only) masked chunk

    auto stageK = [&](int jc, int buf) {
        int j0 = jc << 6;
        #pragma unroll
        for (int c = 0; c < 4; c++) {
            int idx = c*256 + w*64 + lane;   // 16B unit index in [0,1024)
            int row = idx >> 4;              // j within chunk
            int u   = (idx & 15) ^ (row & 7);
            const bf16* src = (u < 8)
                ? kvbh + (size_t)(j0 + row) * 3072 + u * 8
                : kpe  + (size_t)(j0 + row) * 64  + (u - 8) * 8;
            __builtin_amdgcn_global_load_lds((gconst_t*)src,
                (lvoid_t*)&Kl[buf][(c*256 + w*64) * 8], 16, 0, 0);
        }
    };
    auto stageV = [&](int jc, int buf) {
        int j0 = jc << 6;
        #pragma unroll
        for (int c = 0; c < 4; c++) {
            int idx = c*256 + w*64 + lane;   // 16B unit index in [0,1024)
            int row = idx >> 3;              // d in [0,128)
            int u   = (idx & 7) ^ (row & 7);
            const bf16* src = vth + (size_t)row * 4096 + j0 + u * 8;
            __builtin_amdgcn_global_load_lds((gconst_t*)src,
                (lvoid_t*)&Vl[buf][(c*256 + w*64) * 8], 16, 0, 0);
        }
    };

    stageK(0, 0); stageV(0, 0);

    for (int jc = 0; jc < nch; ++jc) {
        __syncthreads();                 // implicit vmcnt(0): chunk jc staged, prev reads done
        if (jc + 1 < nch) { stageK(jc + 1, (jc + 1) & 1); stageV(jc + 1, (jc + 1) & 1); }

        if (jc <= dc) {
            int cur = jc & 1;
            int j0  = jc << 6;
            bool masked = (jc == dc);

            // ---- QK^T swapped: S^T[j][i]; lane holds row i=l15, j = j0+16s+g*4+r
            f32x4 sfr[2][4];   // [mt][s]
            #pragma unroll
            for (int s = 0; s < 4; ++s) {
                int krow = s*16 + l15;
                bf16x8 kf[4];
                #pragma unroll
                for (int c = 0; c < 4; ++c)
                    kf[c] = *reinterpret_cast<const bf16x8*>(
                        &Kl[cur][krow*128 + (((c*4 + g) ^ sw) * 8)]);
                #pragma unroll
                for (int mt = 0; mt < 2; ++mt) {
                    f32x4 acc = {};
                    acc = __builtin_amdgcn_mfma_f32_16x16x32_bf16(kf[0], qf[mt][0], acc, 0, 0, 0);
                    acc = __builtin_amdgcn_mfma_f32_16x16x32_bf16(kf[1], qf[mt][1], acc, 0, 0, 0);
                    acc = __builtin_amdgcn_mfma_f32_16x16x32_bf16(kf[2], qf[mt][2], acc, 0, 0, 0);
                    acc = __builtin_amdgcn_mfma_f32_16x16x32_bf16(kf[3], qf[mt][3], acc, 0, 0, 0);
                    sfr[mt][s] = acc;
                }
            }

            // ---- softmax (in-register) + packed P staging, per m-tile
            bf16x8 pf[2][2];
            #pragma unroll
            for (int mt = 0; mt < 2; ++mt) {
                int i = qrow + mt*16 + l15;     // this lane's q-row
                if (masked) {
                    #pragma unroll
                    for (int s = 0; s < 4; ++s)
                        #pragma unroll
                        for (int r = 0; r < 4; ++r) {
                            int j = j0 + s*16 + g*4 + r;
                            if (j > i) sfr[mt][s][r] = -3e38f;
                        }
                }
                float m01 = fmaxf(fmaxf(sfr[mt][0][0], sfr[mt][0][1]),
                                  fmaxf(sfr[mt][0][2], sfr[mt][0][3]));
                float m23 = fmaxf(fmaxf(sfr[mt][1][0], sfr[mt][1][1]),
                                  fmaxf(sfr[mt][1][2], sfr[mt][1][3]));
                float m45 = fmaxf(fmaxf(sfr[mt][2][0], sfr[mt][2][1]),
                                  fmaxf(sfr[mt][2][2], sfr[mt][2][3]));
                float m67 = fmaxf(fmaxf(sfr[mt][3][0], sfr[mt][3][1]),
                                  fmaxf(sfr[mt][3][2], sfr[mt][3][3]));
                float mloc = fmaxf(fmaxf(m01, m23), fmaxf(m45, m67));
                float mx = fmaxf(mloc, __shfl_xor(mloc, 16));
                mx = fmaxf(mx, __shfl_xor(mx, 32));
                bool need = mx > mrow[mt];
                float mnew = fmaxf(mrow[mt], mx);
                float sfac = __builtin_amdgcn_exp2f(mrow[mt] - mnew);
                mrow[mt] = mnew;
                float psum = 0.f;
                #pragma unroll
                for (int s = 0; s < 4; ++s)
                    #pragma unroll
                    for (int r = 0; r < 4; ++r) {
                        float p = __builtin_amdgcn_exp2f(sfr[mt][s][r] - mnew);
                        sfr[mt][s][r] = p;
                        psum += p;
                    }
                lrow[mt] = lrow[mt] * sfac + psum;
                // packed P writes (b64)
                #pragma unroll
                for (int s = 0; s < 4; ++s) {
                    uint2 uu;
                    uu.x = pack2bf(sfr[mt][s][0], sfr[mt][s][1]);
                    uu.y = pack2bf(sfr[mt][s][2], sfr[mt][s][3]);
                    *reinterpret_cast<uint2*>(&Pl[w][l15 * LPS + s*16 + g*4]) = uu;
                }
                // broadcast sfac (per row i) to O-domain lanes
                if (g == 0) bcast[w][l15] = sfac;
                f32x4 sf4 = *reinterpret_cast<const f32x4*>(&bcast[w][g*4]);
                if (__any(need)) {
                    #pragma unroll
                    for (int dt = 0; dt < 8; ++dt)
                        #pragma unroll
                        for (int r = 0; r < 4; ++r) o[mt][dt][r] *= sf4[r];
                }
                pf[mt][0] = *reinterpret_cast<const bf16x8*>(&Pl[w][l15 * LPS + g * 8]);
                pf[mt][1] = *reinterpret_cast<const bf16x8*>(&Pl[w][l15 * LPS + 32 + g * 8]);
            }

            // ---- PV: O[32q][128d] += P[32q][64j] V[64j][128d]
            #pragma unroll
            for (int dt = 0; dt < 8; ++dt) {
                int vrow = dt*16 + l15;
                bf16x8 va = *reinterpret_cast<const bf16x8*>(
                    &Vl[cur][vrow*64 + ((g ^ sw) * 8)]);
                bf16x8 vb = *reinterpret_cast<const bf16x8*>(
                    &Vl[cur][vrow*64 + (((4 + g) ^ sw) * 8)]);
                o[0][dt] = __builtin_amdgcn_mfma_f32_16x16x32_bf16(pf[0][0], va, o[0][dt], 0, 0, 0);
                o[0][dt] = __builtin_amdgcn_mfma_f32_16x16x32_bf16(pf[0][1], vb, o[0][dt], 0, 0, 0);
                o[1][dt] = __builtin_amdgcn_mfma_f32_16x16x32_bf16(pf[1][0], va, o[1][dt], 0, 0, 0);
                o[1][dt] = __builtin_amdgcn_mfma_f32_16x16x32_bf16(pf[1][1], vb, o[1][dt], 0, 0, 0);
            }
        }
    }

    // ---- epilogue: reduce l across g-lanes, broadcast 1/l to O-domain, store
    #pragma unroll
    for (int mt = 0; mt < 2; ++mt) {
        float l = lrow[mt];
        l += __shfl_xor(l, 16);
        l += __shfl_xor(l, 32);
        float linv = __builtin_amdgcn_rcpf(l);
        if (g == 0) bcast[w][l15] = linv;
        f32x4 li4 = *reinterpret_cast<const f32x4*>(&bcast[w][g*4]);
        #pragma unroll
        for (int r = 0; r < 4; ++r) {
            int i = qrow + mt*16 + g*4 + r;
            #pragma unroll
            for (int dt = 0; dt < 8; ++dt)
                attn[(size_t)i * 2048 + h * 128 + dt*16 + l15] = (bf16)(o[mt][dt][r] * li4[r]);
        }
    }
}

// ---------------------------------------------------------------- launch
extern "C" void kernel_launch(void* const* d_in, const int* in_sizes, int n_in,
                              void* d_out, int out_size, void* d_ws, size_t ws_size,
                              hipStream_t stream) {
    const float* x    = (const float*)d_in[0];
    const float* cosb = (const float*)d_in[1];
    const float* sinb = (const float*)d_in[2];
    // d_in[3] = mask (unused: causal, start_pos=0)
    const float* wq   = (const float*)d_in[4];
    const float* wkva = (const float*)d_in[5];
    const float* kvw  = (const float*)d_in[6];
    const float* wkvb = (const float*)d_in[7];
    const float* wo   = (const float*)d_in[8];
    // d_in[9] = start_pos (0)

    char* ws = (char*)d_ws;
    bf16* x_bf    = (bf16*)(ws + 0);          // 16.7MB; later reused as kvnorm, then attn
    bf16* kvnorm  = (bf16*)(ws + 0);
    bf16* attn    = (bf16*)(ws + 0);
    bf16* wq_bf   = (bf16*)(ws + 16777216);   // [2048][2048] bf16
    bf16* wkva_bf = (bf16*)(ws + 25165824);   // [1088][2048] bf16 — contiguous after wq_bf => B=[3136][2048]
    bf16* wkvb_bf = (bf16*)(ws + 29622272);
    bf16* wo_bf   = (bf16*)(ws + 35913728);
    bf16* qkv     = (bf16*)(ws + 44302336);   // [4096][3136] bf16 (q | kv_full)
    bf16* kpe     = (bf16*)(ws + 69992448);
    bf16* kvb     = (bf16*)(ws + 70516736);
    bf16* vt      = (bf16*)(ws + 95682560);
    // total: 112459776 bytes

    convert_all_kernel<<<dim3(2048), dim3(256), 0, stream>>>(
        x, wq, wkva, wkvb, wo, x_bf, wq_bf, wkva_bf, wkvb_bf, wo_bf);

    // merged q + kv_a projection: [4096][3136] = x_bf @ [3136][2048]^T
    gemm256_kernel<256, true><<<dim3(13, 16), dim3(512), 0, stream>>>(x_bf, wq_bf, qkv, 4096, QKV_N, 2048);

    prep_qkv_kernel<<<dim3(4096), dim3(256), 0, stream>>>(qkv, kvw, cosb, sinb, kvnorm, kpe);

    gemm256_kernel<256, true><<<dim3(12, 16), dim3(512), 0, stream>>>(kvnorm, wkvb_bf, kvb, 4096, 3072, 1024);

    build_vt_kernel<<<dim3(64, 16), dim3(256), 0, stream>>>(kvb, vt);

    attn_kernel<<<dim3(32, 16), dim3(256), 0, stream>>>(qkv, kvb, kpe, vt, attn);

    gemm256_kernel<128, false><<<dim3(16, 16), dim3(512), 0, stream>>>(attn, wo_bf, (float*)d_out, 4096, 2048, 2048);
}

// Round 20
// 319.520 us; speedup vs baseline: 1.1095x; 1.0019x over previous
//
#include <hip/hip_runtime.h>

typedef __bf16 bf16;
typedef __attribute__((ext_vector_type(8))) __bf16 bf16x8;
typedef __attribute__((ext_vector_type(2))) __bf16 bf16x2;
typedef __attribute__((ext_vector_type(4))) float f32x4;
typedef __attribute__((ext_vector_type(4))) int int4v;

typedef __attribute__((address_space(1))) const void gconst_t;
typedef __attribute__((address_space(3))) void lvoid_t;

#define SEQ 4096
#define D_IN 2048
#define NHEADS 16
// SCALE * log2(e): attention computed in exp2 domain
#define QSCALE (0.08838834764831843f * 1.4426950408889634f)
#define RMS_EPS 1e-6f
#define QKV_N 3136   // 2048 (q) + 1088 (kv_full)

__device__ inline unsigned pack2bf(float a, float b) {
    bf16x2 t; t[0] = (bf16)a; t[1] = (bf16)b;
    return __builtin_bit_cast(unsigned, t);
}

// ---------------------------------------------------------------- fused conversions
__device__ inline void conv_seg(const float* __restrict__ in, bf16* __restrict__ out,
                                int n, int i0, int stride) {
    for (int i = i0; i < n; i += stride) {
        float4 v = *reinterpret_cast<const float4*>(in + i);
        bf16 o[4];
        o[0] = (bf16)v.x; o[1] = (bf16)v.y; o[2] = (bf16)v.z; o[3] = (bf16)v.w;
        *reinterpret_cast<uint2*>(out + i) = *reinterpret_cast<uint2*>(o);
    }
}

__global__ __launch_bounds__(256) void convert_all_kernel(
    const float* __restrict__ xs,  const float* __restrict__ wqs,
    const float* __restrict__ was, const float* __restrict__ wbs,
    const float* __restrict__ wos,
    bf16* __restrict__ xd, bf16* __restrict__ wqd, bf16* __restrict__ wad,
    bf16* __restrict__ wbd, bf16* __restrict__ wod) {
    int i0 = (blockIdx.x * 256 + threadIdx.x) * 4;
    int stride = gridDim.x * 256 * 4;
    conv_seg(xs,  xd,  4096 * 2048, i0, stride);
    conv_seg(wqs, wqd, 2048 * 2048, i0, stride);
    conv_seg(was, wad, 1088 * 2048, i0, stride);
    conv_seg(wbs, wbd, 3072 * 1024, i0, stride);
    conv_seg(wos, wod, 2048 * 2048, i0, stride);
}

// ---------------------------------------------------------------- 256-wide GEMM, counted-vmcnt 2-barrier schedule
// (round-7/11/14 proven schedule) + T1 XCD-chunked block swizzle
// (round-17/18 measured: ~9-11 us on the GEMM chain).
template<int BN, bool BF16_OUT>
__global__ __launch_bounds__(512, 2) void gemm256_kernel(
    const bf16* __restrict__ A, const bf16* __restrict__ B, void* __restrict__ Cout,
    int M, int N, int K) {
    constexpr int CB = BN / 64;      // B stage loads per thread (4 or 2)
    constexpr int NF = BN / 64;      // n-frags per wave (4 or 2)
    constexpr int WC = BN / 4;       // cols per wave
    __shared__ __align__(16) bf16 Al[2][256 * 64];
    __shared__ __align__(16) bf16 Bl[2][BN * 64];

    int t    = threadIdx.x;
    int lane = t & 63;
    int w    = t >> 6;        // 0..7
    int wr   = w >> 2;        // 0..1
    int wc   = w & 3;         // 0..3
    int l15  = lane & 15;
    int g    = lane >> 4;

    // XCD-chunked swizzle (bijective: nwg % 8 == 0 for all launches here)
    int nwg = gridDim.x * gridDim.y;
    int lid = (int)blockIdx.x + (int)gridDim.x * (int)blockIdx.y;
    int cpx = nwg >> 3;
    int nid = (lid & 7) * cpx + (lid >> 3);
    int bx  = nid % (int)gridDim.x;
    int by  = nid / (int)gridDim.x;
    int m0 = by * 256;
    int n0 = bx * BN;

    f32x4 acc[8][NF] = {};

    auto stage = [&](int kt, int buf) {
        int k0 = kt << 6;
        #pragma unroll
        for (int c = 0; c < 4; c++) {           // A: 256 rows x 64 cols
            int idx = c * 512 + t;
            int r = idx >> 3;
            int u = (idx & 7) ^ (r & 7);
            const bf16* ga = A + (size_t)(m0 + r) * K + k0 + u * 8;
            __builtin_amdgcn_global_load_lds((gconst_t*)ga,
                (lvoid_t*)&Al[buf][(c * 512 + w * 64) * 8], 16, 0, 0);
        }
        #pragma unroll
        for (int c = 0; c < CB; c++) {          // B: BN rows x 64 cols
            int idx = c * 512 + t;
            int r = idx >> 3;
            int u = (idx & 7) ^ (r & 7);
            int br = n0 + r; if (br >= N) br = N - 1;
            const bf16* gb = B + (size_t)br * K + k0 + u * 8;
            __builtin_amdgcn_global_load_lds((gconst_t*)gb,
                (lvoid_t*)&Bl[buf][(c * 512 + w * 64) * 8], 16, 0, 0);
        }
    };

    int nt = K >> 6;
    stage(0, 0);
    for (int kt = 0; kt < nt; ++kt) {
        int buf = kt & 1;
        if (kt + 1 < nt) {
            stage(kt + 1, buf ^ 1);
            __builtin_amdgcn_sched_barrier(0);
            if constexpr (BN == 256) asm volatile("s_waitcnt vmcnt(8)" ::: "memory");
            else                     asm volatile("s_waitcnt vmcnt(6)" ::: "memory");
            __builtin_amdgcn_sched_barrier(0);
        } else {
            __builtin_amdgcn_sched_barrier(0);
            asm volatile("s_waitcnt vmcnt(0)" ::: "memory");
            __builtin_amdgcn_sched_barrier(0);
        }
        __builtin_amdgcn_s_barrier();

        #pragma unroll
        for (int ks = 0; ks < 2; ++ks) {
            bf16x8 af[8], bfv[NF];
            #pragma unroll
            for (int mt = 0; mt < 8; mt++) {
                int ra = wr * 128 + mt * 16 + l15;
                int u = (ks * 4 + g) ^ (ra & 7);
                af[mt] = *reinterpret_cast<const bf16x8*>(&Al[buf][ra * 64 + u * 8]);
            }
            #pragma unroll
            for (int nf = 0; nf < NF; nf++) {
                int rb = wc * WC + nf * 16 + l15;
                int u = (ks * 4 + g) ^ (rb & 7);
                bfv[nf] = *reinterpret_cast<const bf16x8*>(&Bl[buf][rb * 64 + u * 8]);
            }
            __builtin_amdgcn_s_setprio(1);
            #pragma unroll
            for (int mt = 0; mt < 8; mt++)
                #pragma unroll
                for (int nf = 0; nf < NF; nf++)
                    acc[mt][nf] = __builtin_amdgcn_mfma_f32_16x16x32_bf16(af[mt], bfv[nf], acc[mt][nf], 0, 0, 0);
            __builtin_amdgcn_s_setprio(0);
        }
        __builtin_amdgcn_s_barrier();
    }

    #pragma unroll
    for (int mt = 0; mt < 8; mt++) {
        #pragma unroll
        for (int nf = 0; nf < NF; nf++) {
            int col = n0 + wc * WC + nf * 16 + l15;
            if (col < N) {
                #pragma unroll
                for (int r = 0; r < 4; r++) {
                    int row = m0 + wr * 128 + mt * 16 + g * 4 + r;
                    if (BF16_OUT)
                        ((bf16*)Cout)[(size_t)row * N + col] = (bf16)acc[mt][nf][r];
                    else
                        ((float*)Cout)[(size_t)row * N + col] = acc[mt][nf][r];
                }
            }
        }
    }
}

// ---------------------------------------------------------------- fused q+kv prep
__global__ __launch_bounds__(256) void prep_qkv_kernel(
    bf16* __restrict__ qkv, const float* __restrict__ w,
    const float* __restrict__ cosb, const float* __restrict__ sinb,
    bf16* __restrict__ kvnorm, bf16* __restrict__ kpe) {
    __shared__ float red[4];
    int s = blockIdx.x;
    int t = threadIdx.x;

    // ---- kv part
    const bf16* src = qkv + (size_t)s * QKV_N + 2048;
    float f[4];
    {
        uint2 raw = *reinterpret_cast<const uint2*>(src + t * 4);
        bf16* vb = reinterpret_cast<bf16*>(&raw);
        float ss = 0.f;
        #pragma unroll
        for (int j = 0; j < 4; j++) { f[j] = (float)vb[j]; ss += f[j] * f[j]; }
        #pragma unroll
        for (int m = 1; m < 64; m <<= 1) ss += __shfl_xor(ss, m);
        if ((t & 63) == 0) red[t >> 6] = ss;
    }
    __syncthreads();
    float tot = red[0] + red[1] + red[2] + red[3];
    float rms = rsqrtf(tot * (1.0f / 1024.0f) + RMS_EPS);
    bf16 o[4];
    #pragma unroll
    for (int j = 0; j < 4; j++) o[j] = (bf16)(f[j] * rms * w[t*4 + j]);
    *reinterpret_cast<uint2*>(kvnorm + (size_t)s * 1024 + t * 4) = *reinterpret_cast<uint2*>(o);
    if (t < 16) {
        float e[4];
        #pragma unroll
        for (int j = 0; j < 4; j++) e[j] = (float)src[1024 + t*4 + j];
        int ib = t * 2;
        float c0 = cosb[s*32 + ib],     s0 = sinb[s*32 + ib];
        float c1 = cosb[s*32 + ib + 1], s1 = sinb[s*32 + ib + 1];
        bf16 ko[4];
        ko[0] = (bf16)(e[0]*c0 - e[1]*s0);
        ko[1] = (bf16)(e[0]*s0 + e[1]*c0);
        ko[2] = (bf16)(e[2]*c1 - e[3]*s1);
        ko[3] = (bf16)(e[2]*s1 + e[3]*c1);
        *reinterpret_cast<uint2*>(kpe + (size_t)s * 64 + t * 4) = *reinterpret_cast<uint2*>(ko);
    }

    // ---- q part (in place, cols 0..2047)
    bf16* p = qkv + (size_t)s * QKV_N + t * 8;
    bf16x8 v = *reinterpret_cast<bf16x8*>(p);
    float qf[8];
    #pragma unroll
    for (int j = 0; j < 8; j++) qf[j] = (float)v[j];
    int d0 = (t & 15) * 8;
    if (d0 >= 64) {
        int ib = (d0 - 64) >> 1;
        #pragma unroll
        for (int pr = 0; pr < 4; pr++) {
            float c  = cosb[s * 32 + ib + pr];
            float sn = sinb[s * 32 + ib + pr];
            float xe = qf[pr*2], xo = qf[pr*2 + 1];
            qf[pr*2]     = xe * c - xo * sn;
            qf[pr*2 + 1] = xe * sn + xo * c;
        }
    }
    #pragma unroll
    for (int j = 0; j < 8; j++) v[j] = (bf16)(qf[j] * QSCALE);
    *reinterpret_cast<bf16x8*>(p) = v;
}

// ---------------------------------------------------------------- build Vt[h][128][4096]
__global__ __launch_bounds__(256) void build_vt_kernel(
    const bf16* __restrict__ kvb, bf16* __restrict__ vt) {
    const int LT = 130;
    __shared__ bf16 lt[64 * 130];
    int h  = blockIdx.y;
    int s0 = blockIdx.x * 64;
    int t  = threadIdx.x;
    {
        int row = t >> 2;
        int d0  = (t & 3) * 32;
        const bf16* src = kvb + (size_t)(s0 + row) * 3072 + h * 192 + 64 + d0;
        int4v v0 = *reinterpret_cast<const int4v*>(src);
        int4v v1 = *reinterpret_cast<const int4v*>(src + 8);
        int4v v2 = *reinterpret_cast<const int4v*>(src + 16);
        int4v v3 = *reinterpret_cast<const int4v*>(src + 24);
        int* dst = reinterpret_cast<int*>(&lt[row * LT + d0]);
        int* s0p = reinterpret_cast<int*>(&v0); int* s1p = reinterpret_cast<int*>(&v1);
        int* s2p = reinterpret_cast<int*>(&v2); int* s3p = reinterpret_cast<int*>(&v3);
        #pragma unroll
        for (int j = 0; j < 4; j++) { dst[j] = s0p[j]; dst[4+j] = s1p[j]; dst[8+j] = s2p[j]; dst[12+j] = s3p[j]; }
    }
    __syncthreads();
    int ss = t & 63;
    int db = t >> 6;
    bf16* out = vt + (size_t)h * 128 * 4096 + s0 + ss;
    #pragma unroll
    for (int dd = db; dd < 128; dd += 4)
        out[(size_t)dd * 4096] = lt[ss * LT + dd];
}

// ---------------------------------------------------------------- flash attention
// Round-19 verified best: swapped-QK in-register softmax, K/V double-buffered
// via global_load_lds (swizzled source), one __syncthreads per chunk,
// T1 XCD-chunked grid remap with complementary pairing in the remapped
// domain (constant per-CU pair work; per-head panels L2-local: FETCH 98->23MB).
__global__ __launch_bounds__(256, 2) void attn_kernel(
    const bf16* __restrict__ q,     // [4096][QKV_N]  (roped, *QSCALE, cols 0..2047)
    const bf16* __restrict__ kvb,   // [4096][3072]
    const bf16* __restrict__ kpe,   // [4096][64]
    const bf16* __restrict__ vt,    // [16][128][4096]
    bf16* __restrict__ attn) {      // [4096][2048]
    const int LPS = 72;
    __shared__ __align__(16) bf16 Kl[2][64 * 128];   // 32 KB
    __shared__ __align__(16) bf16 Vl[2][128 * 64];   // 32 KB
    __shared__ __align__(16) bf16 Pl[4][16 * 72];    // 9 KB
    __shared__ __align__(16) float bcast[4][16];     // per-wave row-broadcast

    int L    = (int)blockIdx.x + 32 * (int)blockIdx.y;   // physical slot
    int nid  = (L & 7) * 64 + (L >> 3);                  // XCD-chunked remap
    int bx   = nid & 31;
    int h    = nid >> 5;
    int tile = (h & 1) ? bx : (31 - bx);
    int q0   = tile * 128;
    int t  = threadIdx.x;
    int lane = t & 63;
    int w  = t >> 6;
    int l15 = lane & 15;
    int g   = lane >> 4;
    int sw  = l15 & 7;              // read-side XOR swizzle key
    int qrow = q0 + w * 32;

    const bf16* kvbh = kvb + h * 192;
    const bf16* vth  = vt + (size_t)h * 524288;

    bf16x8 qf[2][4];
    #pragma unroll
    for (int mt = 0; mt < 2; mt++) {
        const bf16* qp = q + (size_t)(qrow + mt*16 + l15) * QKV_N + h * 128 + g * 8;
        #pragma unroll
        for (int c = 0; c < 4; c++) qf[mt][c] = *reinterpret_cast<const bf16x8*>(qp + c * 32);
    }

    f32x4 o[2][8] = {};
    float mrow[2], lrow[2];
    #pragma unroll
    for (int mt = 0; mt < 2; mt++) { mrow[mt] = -3e38f; lrow[mt] = 0.f; }

    int nch = (q0 >> 6) + 2;
    int dc  = (q0 >> 6) + (w >> 1);   // this wave's (only) masked chunk

    auto stageK = [&](int jc, int buf) {
        int j0 = jc << 6;
        #pragma unroll
        for (int c = 0; c < 4; c++) {
            int idx = c*256 + w*64 + lane;   // 16B unit index in [0,1024)
            int row = idx >> 4;              // j within chunk
            int u   = (idx & 15) ^ (row & 7);
            const bf16* src = (u < 8)
                ? kvbh + (size_t)(j0 + row) * 3072 + u * 8
                : kpe  + (size_t)(j0 + row) * 64  + (u - 8) * 8;
            __builtin_amdgcn_global_load_lds((gconst_t*)src,
                (lvoid_t*)&Kl[buf][(c*256 + w*64) * 8], 16, 0, 0);
        }
    };
    auto stageV = [&](int jc, int buf) {
        int j0 = jc << 6;
        #pragma unroll
        for (int c = 0; c < 4; c++) {
            int idx = c*256 + w*64 + lane;   // 16B unit index in [0,1024)
            int row = idx >> 3;              // d in [0,128)
            int u   = (idx & 7) ^ (row & 7);
            const bf16* src = vth + (size_t)row * 4096 + j0 + u * 8;
            __builtin_amdgcn_global_load_lds((gconst_t*)src,
                (lvoid_t*)&Vl[buf][(c*256 + w*64) * 8], 16, 0, 0);
        }
    };

    stageK(0, 0); stageV(0, 0);

    for (int jc = 0; jc < nch; ++jc) {
        __syncthreads();                 // implicit vmcnt(0): chunk jc staged, prev reads done
        if (jc + 1 < nch) { stageK(jc + 1, (jc + 1) & 1); stageV(jc + 1, (jc + 1) & 1); }

        if (jc <= dc) {
            int cur = jc & 1;
            int j0  = jc << 6;
            bool masked = (jc == dc);

            // ---- QK^T swapped: S^T[j][i]; lane holds row i=l15, j = j0+16s+g*4+r
            f32x4 sfr[2][4];   // [mt][s]
            #pragma unroll
            for (int s = 0; s < 4; ++s) {
                int krow = s*16 + l15;
                bf16x8 kf[4];
                #pragma unroll
                for (int c = 0; c < 4; ++c)
                    kf[c] = *reinterpret_cast<const bf16x8*>(
                        &Kl[cur][krow*128 + (((c*4 + g) ^ sw) * 8)]);
                #pragma unroll
                for (int mt = 0; mt < 2; ++mt) {
                    f32x4 acc = {};
                    acc = __builtin_amdgcn_mfma_f32_16x16x32_bf16(kf[0], qf[mt][0], acc, 0, 0, 0);
                    acc = __builtin_amdgcn_mfma_f32_16x16x32_bf16(kf[1], qf[mt][1], acc, 0, 0, 0);
                    acc = __builtin_amdgcn_mfma_f32_16x16x32_bf16(kf[2], qf[mt][2], acc, 0, 0, 0);
                    acc = __builtin_amdgcn_mfma_f32_16x16x32_bf16(kf[3], qf[mt][3], acc, 0, 0, 0);
                    sfr[mt][s] = acc;
                }
            }

            // ---- softmax (in-register) + packed P staging, per m-tile
            bf16x8 pf[2][2];
            #pragma unroll
            for (int mt = 0; mt < 2; ++mt) {
                int i = qrow + mt*16 + l15;     // this lane's q-row
                if (masked) {
                    #pragma unroll
                    for (int s = 0; s < 4; ++s)
                        #pragma unroll
                        for (int r = 0; r < 4; ++r) {
                            int j = j0 + s*16 + g*4 + r;
                            if (j > i) sfr[mt][s][r] = -3e38f;
                        }
                }
                float m01 = fmaxf(fmaxf(sfr[mt][0][0], sfr[mt][0][1]),
                                  fmaxf(sfr[mt][0][2], sfr[mt][0][3]));
                float m23 = fmaxf(fmaxf(sfr[mt][1][0], sfr[mt][1][1]),
                                  fmaxf(sfr[mt][1][2], sfr[mt][1][3]));
                float m45 = fmaxf(fmaxf(sfr[mt][2][0], sfr[mt][2][1]),
                                  fmaxf(sfr[mt][2][2], sfr[mt][2][3]));
                float m67 = fmaxf(fmaxf(sfr[mt][3][0], sfr[mt][3][1]),
                                  fmaxf(sfr[mt][3][2], sfr[mt][3][3]));
                float mloc = fmaxf(fmaxf(m01, m23), fmaxf(m45, m67));
                float mx = fmaxf(mloc, __shfl_xor(mloc, 16));
                mx = fmaxf(mx, __shfl_xor(mx, 32));
                bool need = mx > mrow[mt];
                float mnew = fmaxf(mrow[mt], mx);
                float sfac = __builtin_amdgcn_exp2f(mrow[mt] - mnew);
                mrow[mt] = mnew;
                float psum = 0.f;
                #pragma unroll
                for (int s = 0; s < 4; ++s)
                    #pragma unroll
                    for (int r = 0; r < 4; ++r) {
                        float p = __builtin_amdgcn_exp2f(sfr[mt][s][r] - mnew);
                        sfr[mt][s][r] = p;
                        psum += p;
                    }
                lrow[mt] = lrow[mt] * sfac + psum;
                // packed P writes (b64)
                #pragma unroll
                for (int s = 0; s < 4; ++s) {
                    uint2 uu;
                    uu.x = pack2bf(sfr[mt][s][0], sfr[mt][s][1]);
                    uu.y = pack2bf(sfr[mt][s][2], sfr[mt][s][3]);
                    *reinterpret_cast<uint2*>(&Pl[w][l15 * LPS + s*16 + g*4]) = uu;
                }
                // broadcast sfac (per row i) to O-domain lanes
                if (g == 0) bcast[w][l15] = sfac;
                f32x4 sf4 = *reinterpret_cast<const f32x4*>(&bcast[w][g*4]);
                if (__any(need)) {
                    #pragma unroll
                    for (int dt = 0; dt < 8; ++dt)
                        #pragma unroll
                        for (int r = 0; r < 4; ++r) o[mt][dt][r] *= sf4[r];
                }
                pf[mt][0] = *reinterpret_cast<const bf16x8*>(&Pl[w][l15 * LPS + g * 8]);
                pf[mt][1] = *reinterpret_cast<const bf16x8*>(&Pl[w][l15 * LPS + 32 + g * 8]);
            }

            // ---- PV: O[32q][128d] += P[32q][64j] V[64j][128d]
            #pragma unroll
            for (int dt = 0; dt < 8; ++dt) {
                int vrow = dt*16 + l15;
                bf16x8 va = *reinterpret_cast<const bf16x8*>(
                    &Vl[cur][vrow*64 + ((g ^ sw) * 8)]);
                bf16x8 vb = *reinterpret_cast<const bf16x8*>(
                    &Vl[cur][vrow*64 + (((4 + g) ^ sw) * 8)]);
                o[0][dt] = __builtin_amdgcn_mfma_f32_16x16x32_bf16(pf[0][0], va, o[0][dt], 0, 0, 0);
                o[0][dt] = __builtin_amdgcn_mfma_f32_16x16x32_bf16(pf[0][1], vb, o[0][dt], 0, 0, 0);
                o[1][dt] = __builtin_amdgcn_mfma_f32_16x16x32_bf16(pf[1][0], va, o[1][dt], 0, 0, 0);
                o[1][dt] = __builtin_amdgcn_mfma_f32_16x16x32_bf16(pf[1][1], vb, o[1][dt], 0, 0, 0);
            }
        }
    }

    // ---- epilogue: reduce l across g-lanes, broadcast 1/l to O-domain, store
    #pragma unroll
    for (int mt = 0; mt < 2; ++mt) {
        float l = lrow[mt];
        l += __shfl_xor(l, 16);
        l += __shfl_xor(l, 32);
        float linv = __builtin_amdgcn_rcpf(l);
        if (g == 0) bcast[w][l15] = linv;
        f32x4 li4 = *reinterpret_cast<const f32x4*>(&bcast[w][g*4]);
        #pragma unroll
        for (int r = 0; r < 4; ++r) {
            int i = qrow + mt*16 + g*4 + r;
            #pragma unroll
            for (int dt = 0; dt < 8; ++dt)
                attn[(size_t)i * 2048 + h * 128 + dt*16 + l15] = (bf16)(o[mt][dt][r] * li4[r]);
        }
    }
}

// ---------------------------------------------------------------- launch
extern "C" void kernel_launch(void* const* d_in, const int* in_sizes, int n_in,
                              void* d_out, int out_size, void* d_ws, size_t ws_size,
                              hipStream_t stream) {
    const float* x    = (const float*)d_in[0];
    const float* cosb = (const float*)d_in[1];
    const float* sinb = (const float*)d_in[2];
    // d_in[3] = mask (unused: causal, start_pos=0)
    const float* wq   = (const float*)d_in[4];
    const float* wkva = (const float*)d_in[5];
    const float* kvw  = (const float*)d_in[6];
    const float* wkvb = (const float*)d_in[7];
    const float* wo   = (const float*)d_in[8];
    // d_in[9] = start_pos (0)

    char* ws = (char*)d_ws;
    bf16* x_bf    = (bf16*)(ws + 0);          // 16.7MB; later reused as kvnorm, then attn
    bf16* kvnorm  = (bf16*)(ws + 0);
    bf16* attn    = (bf16*)(ws + 0);
    bf16* wq_bf   = (bf16*)(ws + 16777216);   // [2048][2048] bf16
    bf16* wkva_bf = (bf16*)(ws + 25165824);   // [1088][2048] bf16 — contiguous after wq_bf => B=[3136][2048]
    bf16* wkvb_bf = (bf16*)(ws + 29622272);
    bf16* wo_bf   = (bf16*)(ws + 35913728);
    bf16* qkv     = (bf16*)(ws + 44302336);   // [4096][3136] bf16 (q | kv_full)
    bf16* kpe     = (bf16*)(ws + 69992448);
    bf16* kvb     = (bf16*)(ws + 70516736);
    bf16* vt      = (bf16*)(ws + 95682560);
    // total: 112459776 bytes

    convert_all_kernel<<<dim3(2048), dim3(256), 0, stream>>>(
        x, wq, wkva, wkvb, wo, x_bf, wq_bf, wkva_bf, wkvb_bf, wo_bf);

    // merged q + kv_a projection: [4096][3136] = x_bf @ [3136][2048]^T
    gemm256_kernel<256, true><<<dim3(13, 16), dim3(512), 0, stream>>>(x_bf, wq_bf, qkv, 4096, QKV_N, 2048);

    prep_qkv_kernel<<<dim3(4096), dim3(256), 0, stream>>>(qkv, kvw, cosb, sinb, kvnorm, kpe);

    gemm256_kernel<256, true><<<dim3(12, 16), dim3(512), 0, stream>>>(kvnorm, wkvb_bf, kvb, 4096, 3072, 1024);

    build_vt_kernel<<<dim3(64, 16), dim3(256), 0, stream>>>(kvb, vt);

    attn_kernel<<<dim3(32, 16), dim3(256), 0, stream>>>(qkv, kvb, kpe, vt, attn);

    gemm256_kernel<128, false><<<dim3(16, 16), dim3(512), 0, stream>>>(attn, wo_bf, (float*)d_out, 4096, 2048, 2048);
}